// Round 1
// baseline (3282.441 us; speedup 1.0000x reference)
//
#include <hip/hip_runtime.h>

#define FEAT 128

// ---------------------------------------------------------------------------
// Phase 1: edge-parallel scatter-add.  One thread handles (edge, 4 columns).
// Lanes 0-31 of a wave cover one full 512B row (coalesced float4 gather).
// ---------------------------------------------------------------------------
__global__ __launch_bounds__(256) void scatter_kernel(
    const float* __restrict__ x, const int* __restrict__ src,
    const int* __restrict__ dst, float* __restrict__ agg, int E)
{
    long tid = (long)blockIdx.x * blockDim.x + threadIdx.x;
    long e = tid >> 5;
    int  c = (int)(tid & 31) << 2;
    if (e >= E) return;
    int s = src[e];
    int d = dst[e];
    const float4 v = *reinterpret_cast<const float4*>(x + (long)s * FEAT + c);
    float* p = agg + (long)d * FEAT + c;
    atomicAdd(p + 0, v.x);
    atomicAdd(p + 1, v.y);
    atomicAdd(p + 2, v.z);
    atomicAdd(p + 3, v.w);
}

// ---------------------------------------------------------------------------
// Phase 2: out[n,:] = relu( sum_r agg_r[n,:] @ W_r )
// f32 vector-FMA GEMM (no fp32 MFMA on CDNA4).
// Block: 256 threads, BM=64 rows, BN=128 (full), K chunked by 16 in LDS.
// Thread micro-tile: 8 rows x 4 cols.  A staged transposed (k-major) so the
// 8-row A fragment is two ds_read_b128 broadcasts.
// ---------------------------------------------------------------------------
template<int NREL>
__global__ __launch_bounds__(256) void gemm_kernel(
    const float* __restrict__ a0, const float* __restrict__ a1,
    const float* __restrict__ a2,
    const float* __restrict__ w0, const float* __restrict__ w1,
    const float* __restrict__ w2,
    float* __restrict__ out, int N, int accum, int relu)
{
    __shared__ float As[16][68];   // k-major, padded (+4) to break write conflicts
    __shared__ float Bs[16][128];

    const float* aggs[3] = {a0, a1, a2};
    const float* wmats[3] = {w0, w1, w2};

    const int t = threadIdx.x;
    const int row0 = blockIdx.x * 64;
    const int cg = t & 31;     // col group: 4 cols each
    const int rg = t >> 5;     // row group: 8 rows each

    // A-staging mapping: thread -> (row 0..63, 4 consecutive k's)
    const int arow = t >> 2;
    const int ac4  = (t & 3) << 2;

    float acc[8][4];
    #pragma unroll
    for (int i = 0; i < 8; ++i)
        #pragma unroll
        for (int j = 0; j < 4; ++j) acc[i][j] = 0.f;

    #pragma unroll
    for (int r = 0; r < NREL; ++r) {
        const float* __restrict__ A = aggs[r];
        const float* __restrict__ W = wmats[r];
        for (int kb = 0; kb < 8; ++kb) {
            // load A chunk (guarded), transpose into LDS
            float4 va = make_float4(0.f, 0.f, 0.f, 0.f);
            const int grow = row0 + arow;
            if (grow < N)
                va = *reinterpret_cast<const float4*>(
                    A + (long)grow * FEAT + kb * 16 + ac4);
            __syncthreads();   // previous chunk's reads complete
            As[ac4 + 0][arow] = va.x;
            As[ac4 + 1][arow] = va.y;
            As[ac4 + 2][arow] = va.z;
            As[ac4 + 3][arow] = va.w;
            // load B chunk (16 x 128)
            {
                const int bk = t >> 5;            // 0..7
                const int bc = (t & 31) << 2;     // 0..124
                *reinterpret_cast<float4*>(&Bs[bk][bc]) =
                    *reinterpret_cast<const float4*>(W + (long)(kb * 16 + bk) * FEAT + bc);
                *reinterpret_cast<float4*>(&Bs[bk + 8][bc]) =
                    *reinterpret_cast<const float4*>(W + (long)(kb * 16 + bk + 8) * FEAT + bc);
            }
            __syncthreads();

            #pragma unroll
            for (int k = 0; k < 16; ++k) {
                float a[8];
                #pragma unroll
                for (int i = 0; i < 8; ++i) a[i] = As[k][rg * 8 + i];
                const float4 b = *reinterpret_cast<const float4*>(&Bs[k][cg * 4]);
                #pragma unroll
                for (int i = 0; i < 8; ++i) {
                    acc[i][0] += a[i] * b.x;
                    acc[i][1] += a[i] * b.y;
                    acc[i][2] += a[i] * b.z;
                    acc[i][3] += a[i] * b.w;
                }
            }
        }
    }

    // epilogue
    #pragma unroll
    for (int i = 0; i < 8; ++i) {
        const int grow = row0 + rg * 8 + i;
        if (grow >= N) continue;
        float* p = out + (long)grow * FEAT + cg * 4;
        float4 o = make_float4(acc[i][0], acc[i][1], acc[i][2], acc[i][3]);
        if (accum) {
            const float4 prev = *reinterpret_cast<const float4*>(p);
            o.x += prev.x; o.y += prev.y; o.z += prev.z; o.w += prev.w;
        }
        if (relu) {
            o.x = fmaxf(o.x, 0.f); o.y = fmaxf(o.y, 0.f);
            o.z = fmaxf(o.z, 0.f); o.w = fmaxf(o.w, 0.f);
        }
        *reinterpret_cast<float4*>(p) = o;
    }
}

// ---------------------------------------------------------------------------
extern "C" void kernel_launch(void* const* d_in, const int* in_sizes, int n_in,
                              void* d_out, int out_size, void* d_ws, size_t ws_size,
                              hipStream_t stream)
{
    const float* x  = (const float*)d_in[0];
    const float* W0 = (const float*)d_in[1];
    const float* W1 = (const float*)d_in[2];
    const float* W2 = (const float*)d_in[3];
    const int* src0 = (const int*)d_in[4];
    const int* dst0 = (const int*)d_in[5];
    const int* src1 = (const int*)d_in[6];
    const int* dst1 = (const int*)d_in[7];
    const int* src2 = (const int*)d_in[8];
    const int* dst2 = (const int*)d_in[9];
    float* out = (float*)d_out;

    const int N  = in_sizes[0] / FEAT;
    const int E0 = in_sizes[4];
    const int E1 = in_sizes[6];
    const int E2 = in_sizes[8];

    const size_t plane_elems = (size_t)N * FEAT;
    const size_t plane_bytes = plane_elems * sizeof(float);
    float* agg = (float*)d_ws;

    const int gemm_blocks = (N + 63) / 64;

    auto sgrid = [](int E) { return dim3(((long)E * 32 + 255) / 256); };

    if (ws_size >= 3 * plane_bytes) {
        // fused path: 3 agg planes, one GEMM
        hipMemsetAsync(d_ws, 0, 3 * plane_bytes, stream);
        float* agg0 = agg;
        float* agg1 = agg + plane_elems;
        float* agg2 = agg + 2 * plane_elems;
        scatter_kernel<<<sgrid(E0), 256, 0, stream>>>(x, src0, dst0, agg0, E0);
        scatter_kernel<<<sgrid(E1), 256, 0, stream>>>(x, src1, dst1, agg1, E1);
        scatter_kernel<<<sgrid(E2), 256, 0, stream>>>(x, src2, dst2, agg2, E2);
        gemm_kernel<3><<<gemm_blocks, 256, 0, stream>>>(
            agg0, agg1, agg2, W0, W1, W2, out, N, 0, 1);
    } else {
        // sequential path: one agg plane reused per relation
        const float* srcs[3] = {(const float*)src0, (const float*)src1, (const float*)src2};
        const int* srca[3] = {src0, src1, src2};
        const int* dsta[3] = {dst0, dst1, dst2};
        const float* wa[3] = {W0, W1, W2};
        const int Ea[3] = {E0, E1, E2};
        (void)srcs;
        for (int r = 0; r < 3; ++r) {
            hipMemsetAsync(d_ws, 0, plane_bytes, stream);
            scatter_kernel<<<sgrid(Ea[r]), 256, 0, stream>>>(x, srca[r], dsta[r], agg, Ea[r]);
            gemm_kernel<1><<<gemm_blocks, 256, 0, stream>>>(
                agg, agg, agg, wa[r], wa[r], wa[r], out, N, r > 0, r == 2);
        }
    }
}

// Round 2
// 630.292 us; speedup vs baseline: 5.2078x; 5.2078x over previous
//
#include <hip/hip_runtime.h>

#define FEAT 128

// ---------------------------------------------------------------------------
// CSR build: histogram of dst
// ---------------------------------------------------------------------------
__global__ __launch_bounds__(256) void hist_kernel(
    const int* __restrict__ dst, int* __restrict__ cnt, int E)
{
    int e = blockIdx.x * 256 + threadIdx.x;
    if (e < E) atomicAdd(&cnt[dst[e]], 1);
}

// ---------------------------------------------------------------------------
// CSR build: exclusive scan of counts -> row_start + cursor copy.
// One block (1024 threads) per relation; tiled block-scan, coalesced loads.
// ---------------------------------------------------------------------------
__global__ __launch_bounds__(1024) void scan_kernel(
    const int* __restrict__ cnt, int* __restrict__ rs, int* __restrict__ cur, int n)
{
    const int rel = blockIdx.x;
    const int* c = cnt + (size_t)rel * n;
    int* rsr  = rs  + (size_t)rel * (n + 1);
    int* curr = cur + (size_t)rel * n;
    const int t = threadIdx.x;
    const int lane = t & 63, wid = t >> 6;
    __shared__ int wsum[16];
    __shared__ int stot;
    int running = 0;
    for (int base = 0; base < n; base += 1024) {
        const int i = base + t;
        const int v = (i < n) ? c[i] : 0;
        int iv = v;
        #pragma unroll
        for (int off = 1; off < 64; off <<= 1) {
            int u = __shfl_up(iv, off);
            if (lane >= off) iv += u;
        }
        if (lane == 63) wsum[wid] = iv;
        __syncthreads();
        if (t == 0) {
            int run = 0;
            #pragma unroll
            for (int k = 0; k < 16; ++k) { int tmp = wsum[k]; wsum[k] = run; run += tmp; }
            stot = run;
        }
        __syncthreads();
        const int excl = running + wsum[wid] + (iv - v);
        if (i < n) { rsr[i] = excl; curr[i] = excl; }
        running += stot;
        __syncthreads();
    }
    if (t == 0) rsr[n] = running;
}

// ---------------------------------------------------------------------------
// CSR build: fill src indices grouped by dst
// ---------------------------------------------------------------------------
__global__ __launch_bounds__(256) void fill_kernel(
    const int* __restrict__ src, const int* __restrict__ dst,
    int* __restrict__ cur, int* __restrict__ es, int E)
{
    int e = blockIdx.x * 256 + threadIdx.x;
    if (e < E) {
        int p = atomicAdd(&cur[dst[e]], 1);
        es[p] = src[e];
    }
}

// ---------------------------------------------------------------------------
// H_r = x @ W_r  (r = blockIdx.y).  f32 vector-FMA GEMM.
// Block: 256 threads, 64 rows x 128 cols, K=128 chunked by 16 in LDS.
// ---------------------------------------------------------------------------
__global__ __launch_bounds__(256) void gemm3_kernel(
    const float* __restrict__ x,
    const float* __restrict__ w0, const float* __restrict__ w1,
    const float* __restrict__ w2,
    float* __restrict__ H, int N, long plane)
{
    __shared__ float As[16][68];   // k-major, padded
    __shared__ float Bs[16][128];

    const float* Ws[3] = {w0, w1, w2};
    const float* __restrict__ W = Ws[blockIdx.y];
    float* __restrict__ out = H + (long)blockIdx.y * plane;

    const int t = threadIdx.x;
    const int row0 = blockIdx.x * 64;
    const int cg = t & 31;     // 4 cols each
    const int rg = t >> 5;     // 8 rows each
    const int arow = t >> 2;
    const int ac4  = (t & 3) << 2;

    float acc[8][4];
    #pragma unroll
    for (int i = 0; i < 8; ++i)
        #pragma unroll
        for (int j = 0; j < 4; ++j) acc[i][j] = 0.f;

    for (int kb = 0; kb < 8; ++kb) {
        float4 va = make_float4(0.f, 0.f, 0.f, 0.f);
        const int grow = row0 + arow;
        if (grow < N)
            va = *reinterpret_cast<const float4*>(
                x + (long)grow * FEAT + kb * 16 + ac4);
        __syncthreads();
        As[ac4 + 0][arow] = va.x;
        As[ac4 + 1][arow] = va.y;
        As[ac4 + 2][arow] = va.z;
        As[ac4 + 3][arow] = va.w;
        {
            const int bk = t >> 5;
            const int bc = (t & 31) << 2;
            *reinterpret_cast<float4*>(&Bs[bk][bc]) =
                *reinterpret_cast<const float4*>(W + (long)(kb * 16 + bk) * FEAT + bc);
            *reinterpret_cast<float4*>(&Bs[bk + 8][bc]) =
                *reinterpret_cast<const float4*>(W + (long)(kb * 16 + bk + 8) * FEAT + bc);
        }
        __syncthreads();

        #pragma unroll
        for (int k = 0; k < 16; ++k) {
            float a[8];
            #pragma unroll
            for (int i = 0; i < 8; ++i) a[i] = As[k][rg * 8 + i];
            const float4 b = *reinterpret_cast<const float4*>(&Bs[k][cg * 4]);
            #pragma unroll
            for (int i = 0; i < 8; ++i) {
                acc[i][0] += a[i] * b.x;
                acc[i][1] += a[i] * b.y;
                acc[i][2] += a[i] * b.z;
                acc[i][3] += a[i] * b.w;
            }
        }
    }

    #pragma unroll
    for (int i = 0; i < 8; ++i) {
        const int grow = row0 + rg * 8 + i;
        if (grow >= N) continue;
        *reinterpret_cast<float4*>(out + (long)grow * FEAT + cg * 4) =
            make_float4(acc[i][0], acc[i][1], acc[i][2], acc[i][3]);
    }
}

// ---------------------------------------------------------------------------
// Gather-aggregate + relu: one wave per dst row.
// out[d,:] = relu( sum_r sum_{e in in_r(d)} H_r[src_e, :] )
// 64 lanes x float2 = one coalesced 512B row per edge.
// ---------------------------------------------------------------------------
__global__ __launch_bounds__(256) void gather_out_kernel(
    const float* __restrict__ H,
    const int* __restrict__ rs0, const int* __restrict__ es0,
    const int* __restrict__ rs1, const int* __restrict__ es1,
    const int* __restrict__ rs2, const int* __restrict__ es2,
    float* __restrict__ out, int N, long plane)
{
    const int w = blockIdx.x * (blockDim.x >> 6) + (threadIdx.x >> 6);
    if (w >= N) return;
    const int lane = threadIdx.x & 63;
    const int coff = lane * 2;

    float2 acc = make_float2(0.f, 0.f);
    const int* rss[3] = {rs0, rs1, rs2};
    const int* ess[3] = {es0, es1, es2};

    #pragma unroll
    for (int r = 0; r < 3; ++r) {
        const float* __restrict__ Hr = H + (long)r * plane;
        const int* __restrict__ es = ess[r];
        int j = rss[r][w];
        const int jend = rss[r][w + 1];
        for (; j + 2 <= jend; j += 2) {
            const int s0 = es[j];
            const int s1 = es[j + 1];
            const float2 a = *reinterpret_cast<const float2*>(Hr + (long)s0 * FEAT + coff);
            const float2 b = *reinterpret_cast<const float2*>(Hr + (long)s1 * FEAT + coff);
            acc.x += a.x + b.x;
            acc.y += a.y + b.y;
        }
        if (j < jend) {
            const int s0 = es[j];
            const float2 a = *reinterpret_cast<const float2*>(Hr + (long)s0 * FEAT + coff);
            acc.x += a.x;
            acc.y += a.y;
        }
    }

    *reinterpret_cast<float2*>(out + (long)w * FEAT + coff) =
        make_float2(fmaxf(acc.x, 0.f), fmaxf(acc.y, 0.f));
}

// ---------------------------------------------------------------------------
// Fallback (round-1) kernels, used only if ws is too small for CSR path
// ---------------------------------------------------------------------------
__global__ __launch_bounds__(256) void scatter_kernel(
    const float* __restrict__ x, const int* __restrict__ src,
    const int* __restrict__ dst, float* __restrict__ agg, int E)
{
    long tid = (long)blockIdx.x * blockDim.x + threadIdx.x;
    long e = tid >> 5;
    int  c = (int)(tid & 31) << 2;
    if (e >= E) return;
    int s = src[e];
    int d = dst[e];
    const float4 v = *reinterpret_cast<const float4*>(x + (long)s * FEAT + c);
    float* p = agg + (long)d * FEAT + c;
    atomicAdd(p + 0, v.x);
    atomicAdd(p + 1, v.y);
    atomicAdd(p + 2, v.z);
    atomicAdd(p + 3, v.w);
}

__global__ __launch_bounds__(256) void gemm_acc_kernel(
    const float* __restrict__ A, const float* __restrict__ W,
    float* __restrict__ out, int N, int accum, int relu)
{
    __shared__ float As[16][68];
    __shared__ float Bs[16][128];
    const int t = threadIdx.x;
    const int row0 = blockIdx.x * 64;
    const int cg = t & 31;
    const int rg = t >> 5;
    const int arow = t >> 2;
    const int ac4  = (t & 3) << 2;
    float acc[8][4];
    #pragma unroll
    for (int i = 0; i < 8; ++i)
        #pragma unroll
        for (int j = 0; j < 4; ++j) acc[i][j] = 0.f;
    for (int kb = 0; kb < 8; ++kb) {
        float4 va = make_float4(0.f, 0.f, 0.f, 0.f);
        const int grow = row0 + arow;
        if (grow < N)
            va = *reinterpret_cast<const float4*>(A + (long)grow * FEAT + kb * 16 + ac4);
        __syncthreads();
        As[ac4 + 0][arow] = va.x;
        As[ac4 + 1][arow] = va.y;
        As[ac4 + 2][arow] = va.z;
        As[ac4 + 3][arow] = va.w;
        {
            const int bk = t >> 5;
            const int bc = (t & 31) << 2;
            *reinterpret_cast<float4*>(&Bs[bk][bc]) =
                *reinterpret_cast<const float4*>(W + (long)(kb * 16 + bk) * FEAT + bc);
            *reinterpret_cast<float4*>(&Bs[bk + 8][bc]) =
                *reinterpret_cast<const float4*>(W + (long)(kb * 16 + bk + 8) * FEAT + bc);
        }
        __syncthreads();
        #pragma unroll
        for (int k = 0; k < 16; ++k) {
            float a[8];
            #pragma unroll
            for (int i = 0; i < 8; ++i) a[i] = As[k][rg * 8 + i];
            const float4 b = *reinterpret_cast<const float4*>(&Bs[k][cg * 4]);
            #pragma unroll
            for (int i = 0; i < 8; ++i) {
                acc[i][0] += a[i] * b.x;
                acc[i][1] += a[i] * b.y;
                acc[i][2] += a[i] * b.z;
                acc[i][3] += a[i] * b.w;
            }
        }
    }
    #pragma unroll
    for (int i = 0; i < 8; ++i) {
        const int grow = row0 + rg * 8 + i;
        if (grow >= N) continue;
        float* p = out + (long)grow * FEAT + cg * 4;
        float4 o = make_float4(acc[i][0], acc[i][1], acc[i][2], acc[i][3]);
        if (accum) {
            const float4 prev = *reinterpret_cast<const float4*>(p);
            o.x += prev.x; o.y += prev.y; o.z += prev.z; o.w += prev.w;
        }
        if (relu) {
            o.x = fmaxf(o.x, 0.f); o.y = fmaxf(o.y, 0.f);
            o.z = fmaxf(o.z, 0.f); o.w = fmaxf(o.w, 0.f);
        }
        *reinterpret_cast<float4*>(p) = o;
    }
}

// ---------------------------------------------------------------------------
extern "C" void kernel_launch(void* const* d_in, const int* in_sizes, int n_in,
                              void* d_out, int out_size, void* d_ws, size_t ws_size,
                              hipStream_t stream)
{
    const float* x  = (const float*)d_in[0];
    const float* W0 = (const float*)d_in[1];
    const float* W1 = (const float*)d_in[2];
    const float* W2 = (const float*)d_in[3];
    const int* src0 = (const int*)d_in[4];
    const int* dst0 = (const int*)d_in[5];
    const int* src1 = (const int*)d_in[6];
    const int* dst1 = (const int*)d_in[7];
    const int* src2 = (const int*)d_in[8];
    const int* dst2 = (const int*)d_in[9];
    float* out = (float*)d_out;

    const int N  = in_sizes[0] / FEAT;
    const int E0 = in_sizes[4];
    const int E1 = in_sizes[6];
    const int E2 = in_sizes[8];

    const long plane = (long)N * FEAT;
    const size_t plane_bytes = (size_t)plane * sizeof(float);

    // workspace layout
    float* H = (float*)d_ws;                       // 3 * plane floats
    int* cnt = (int*)(H + 3 * plane);              // 3 * N
    int* rs  = cnt + 3 * (size_t)N;                // 3 * (N+1)
    int* cur = rs + 3 * (size_t)(N + 1);           // 3 * N
    int* es  = cur + 3 * (size_t)N;                // E0+E1+E2
    const size_t needed = 3 * plane_bytes +
        ((size_t)3 * N + 3 * (size_t)(N + 1) + 3 * (size_t)N +
         (size_t)E0 + E1 + E2) * sizeof(int);

    const int gemm_blocks = (N + 63) / 64;

    if (ws_size >= needed) {
        // ---- CSR + gather path ----
        // 1) H_r = x @ W_r
        gemm3_kernel<<<dim3(gemm_blocks, 3), 256, 0, stream>>>(
            x, W0, W1, W2, H, N, plane);
        // 2) CSR build
        hipMemsetAsync(cnt, 0, 3 * (size_t)N * sizeof(int), stream);
        hist_kernel<<<(E0 + 255) / 256, 256, 0, stream>>>(dst0, cnt,         E0);
        hist_kernel<<<(E1 + 255) / 256, 256, 0, stream>>>(dst1, cnt + N,     E1);
        hist_kernel<<<(E2 + 255) / 256, 256, 0, stream>>>(dst2, cnt + 2 * N, E2);
        scan_kernel<<<3, 1024, 0, stream>>>(cnt, rs, cur, N);
        int* es0 = es;
        int* es1 = es0 + E0;
        int* es2 = es1 + E1;
        fill_kernel<<<(E0 + 255) / 256, 256, 0, stream>>>(src0, dst0, cur,         es0, E0);
        fill_kernel<<<(E1 + 255) / 256, 256, 0, stream>>>(src1, dst1, cur + N,     es1, E1);
        fill_kernel<<<(E2 + 255) / 256, 256, 0, stream>>>(src2, dst2, cur + 2 * N, es2, E2);
        // 3) gather + relu
        const int gblocks = (N + 3) / 4;   // 4 waves (rows) per block
        gather_out_kernel<<<gblocks, 256, 0, stream>>>(
            H, rs, es0, rs + (N + 1), es1, rs + 2 * (N + 1), es2, out, N, plane);
    } else {
        // ---- fallback: sequential scatter + GEMM (round-1 path) ----
        float* agg = (float*)d_ws;
        const int* srca[3] = {src0, src1, src2};
        const int* dsta[3] = {dst0, dst1, dst2};
        const float* wa[3] = {W0, W1, W2};
        const int Ea[3] = {E0, E1, E2};
        for (int r = 0; r < 3; ++r) {
            hipMemsetAsync(d_ws, 0, plane_bytes, stream);
            scatter_kernel<<<((long)Ea[r] * 32 + 255) / 256, 256, 0, stream>>>(
                x, srca[r], dsta[r], agg, Ea[r]);
            gemm_acc_kernel<<<gemm_blocks, 256, 0, stream>>>(
                agg, wa[r], out, N, r > 0, r == 2);
        }
    }
}

// Round 3
// 555.890 us; speedup vs baseline: 5.9048x; 1.1338x over previous
//
#include <hip/hip_runtime.h>
#include <hip/hip_fp16.h>

#define FEAT 128

typedef _Float16 f16x8 __attribute__((ext_vector_type(8)));
typedef float f32x4 __attribute__((ext_vector_type(4)));

// ---------------------------------------------------------------------------
// W transpose + f32->f16 convert: Wt[r][n][k] = (f16) W_r[k][n]
// ---------------------------------------------------------------------------
__global__ __launch_bounds__(256) void convw_kernel(
    const float* __restrict__ w0, const float* __restrict__ w1,
    const float* __restrict__ w2, _Float16* __restrict__ Wt)
{
    const int idx = blockIdx.x * 256 + threadIdx.x;   // [0, 3*128*128)
    if (idx >= 3 * FEAT * FEAT) return;
    const int r = idx >> 14;
    const int n = (idx >> 7) & 127;
    const int k = idx & 127;
    const float* W = (r == 0) ? w0 : (r == 1) ? w1 : w2;
    Wt[idx] = (_Float16)W[k * FEAT + n];
}

// ---------------------------------------------------------------------------
// CSR build: histogram of dst (grid.y = relation)
// ---------------------------------------------------------------------------
__global__ __launch_bounds__(256) void hist3_kernel(
    const int* __restrict__ d0, const int* __restrict__ d1,
    const int* __restrict__ d2, int* __restrict__ cnt,
    int N, int E0, int E1, int E2)
{
    const int r = blockIdx.y;
    const int* d = (r == 0) ? d0 : (r == 1) ? d1 : d2;
    const int E = (r == 0) ? E0 : (r == 1) ? E1 : E2;
    const int e = blockIdx.x * 256 + threadIdx.x;
    if (e < E) atomicAdd(&cnt[(size_t)r * N + d[e]], 1);
}

// ---------------------------------------------------------------------------
// Scan phase A: per-chunk (4096 counts) sums
// ---------------------------------------------------------------------------
__global__ __launch_bounds__(256) void chunk_sum_kernel(
    const int* __restrict__ cnt, int* __restrict__ bsum, int n, int nch)
{
    const int rel = blockIdx.y, cb = blockIdx.x, t = threadIdx.x;
    const int* c = cnt + (size_t)rel * n;
    const int tb = cb * 4096 + t * 16;
    int s = 0;
    #pragma unroll
    for (int i = 0; i < 16; ++i) {
        const int idx = tb + i;
        if (idx < n) s += c[idx];
    }
    const int lane = t & 63, wv = t >> 6;
    #pragma unroll
    for (int o = 32; o > 0; o >>= 1) s += __shfl_down(s, o);
    __shared__ int wsum[4];
    if (lane == 0) wsum[wv] = s;
    __syncthreads();
    if (t == 0) bsum[rel * nch + cb] = wsum[0] + wsum[1] + wsum[2] + wsum[3];
}

// ---------------------------------------------------------------------------
// Scan phase B: exclusive scan of chunk sums (tiny), writes rs[rel][N]=total
// ---------------------------------------------------------------------------
__global__ __launch_bounds__(64) void chunk_scan_kernel(
    int* __restrict__ bsum, int* __restrict__ rs, int n, int nch)
{
    const int r = threadIdx.x;
    if (r < 3) {
        int run = 0;
        for (int i = 0; i < nch; ++i) {
            const int tmp = bsum[r * nch + i];
            bsum[r * nch + i] = run;
            run += tmp;
        }
        rs[(size_t)r * (n + 1) + n] = run;
    }
}

// ---------------------------------------------------------------------------
// Scan phase C: per-chunk local exclusive scan + chunk offset -> rs, cur
// ---------------------------------------------------------------------------
__global__ __launch_bounds__(256) void scan_chunk_kernel(
    const int* __restrict__ cnt, const int* __restrict__ bsum,
    int* __restrict__ rs, int* __restrict__ cur, int n, int nch)
{
    const int rel = blockIdx.y, cb = blockIdx.x, t = threadIdx.x;
    const int* c = cnt + (size_t)rel * n;
    int* rsr  = rs  + (size_t)rel * (n + 1);
    int* curr = cur + (size_t)rel * n;
    const int tb = cb * 4096 + t * 16;
    int v[16];
    int s = 0;
    #pragma unroll
    for (int i = 0; i < 16; ++i) {
        const int idx = tb + i;
        const int x_ = (idx < n) ? c[idx] : 0;
        v[i] = s;
        s += x_;
    }
    const int lane = t & 63, wv = t >> 6;
    int ps = s;
    #pragma unroll
    for (int o = 1; o < 64; o <<= 1) {
        const int u = __shfl_up(ps, o);
        if (lane >= o) ps += u;
    }
    __shared__ int wtot[4];
    if (lane == 63) wtot[wv] = ps;
    __syncthreads();
    int woff = 0;
    #pragma unroll
    for (int k = 0; k < 4; ++k)
        if (k < wv) woff += wtot[k];
    const int toff = bsum[rel * nch + cb] + woff + (ps - s);
    #pragma unroll
    for (int i = 0; i < 16; ++i) {
        const int idx = tb + i;
        if (idx < n) {
            const int e = toff + v[i];
            rsr[idx] = e;
            curr[idx] = e;
        }
    }
}

// ---------------------------------------------------------------------------
// CSR build: fill src indices grouped by dst (grid.y = relation)
// ---------------------------------------------------------------------------
__global__ __launch_bounds__(256) void fill3_kernel(
    const int* __restrict__ s0, const int* __restrict__ d0,
    const int* __restrict__ s1, const int* __restrict__ d1,
    const int* __restrict__ s2, const int* __restrict__ d2,
    int* __restrict__ cur,
    int* __restrict__ es0, int* __restrict__ es1, int* __restrict__ es2,
    int N, int E0, int E1, int E2)
{
    const int r = blockIdx.y;
    const int* src = (r == 0) ? s0 : (r == 1) ? s1 : s2;
    const int* dst = (r == 0) ? d0 : (r == 1) ? d1 : d2;
    int* es = (r == 0) ? es0 : (r == 1) ? es1 : es2;
    const int E = (r == 0) ? E0 : (r == 1) ? E1 : E2;
    const int e = blockIdx.x * 256 + threadIdx.x;
    if (e < E) {
        const int p = atomicAdd(&cur[(size_t)r * N + dst[e]], 1);
        es[p] = src[e];
    }
}

// ---------------------------------------------------------------------------
// H_r = x @ W_r for r=0..2, f16 MFMA, operand-swapped so each lane's C/D
// fragment is 4 consecutive columns of ONE H row (pairs -> __half2 stores).
//   D = A*B, A = Wt fragment (n-rows x k), B = x^T fragment (k x m-cols)
//   D[n][m]: lane holds m = lane&15 (H row), n = (lane>>4)*4 + reg (H col).
// Block = 4 waves, each wave: 16 H rows x 128 cols x 3 relations.
// ---------------------------------------------------------------------------
__global__ __launch_bounds__(256) void h3_kernel(
    const float* __restrict__ x, const _Float16* __restrict__ Wt,
    __half* __restrict__ H, int N, long plane)
{
    const int t = threadIdx.x;
    const int wv = t >> 6;
    const int l = t & 63;
    const int mtiles = (N + 15) >> 4;
    const int m16 = blockIdx.x * 4 + wv;
    if (m16 >= mtiles) return;
    const int lm = l & 15;        // H row within tile (D col)
    const int g  = l >> 4;        // k-group; D row group = g*4
    const int grow = m16 * 16 + lm;
    const int lrow = (grow < N) ? grow : (N - 1);
    const float* __restrict__ xr = x + (long)lrow * FEAT;

    f32x4 acc[3][8];
    #pragma unroll
    for (int r = 0; r < 3; ++r)
        #pragma unroll
        for (int nt = 0; nt < 8; ++nt)
            acc[r][nt] = 0;

    #pragma unroll
    for (int kq = 0; kq < 4; ++kq) {
        const int k0 = kq * 32 + g * 8;
        const float4 xa = *reinterpret_cast<const float4*>(xr + k0);
        const float4 xb = *reinterpret_cast<const float4*>(xr + k0 + 4);
        f16x8 bfrag;
        bfrag[0] = (_Float16)xa.x; bfrag[1] = (_Float16)xa.y;
        bfrag[2] = (_Float16)xa.z; bfrag[3] = (_Float16)xa.w;
        bfrag[4] = (_Float16)xb.x; bfrag[5] = (_Float16)xb.y;
        bfrag[6] = (_Float16)xb.z; bfrag[7] = (_Float16)xb.w;
        #pragma unroll
        for (int r = 0; r < 3; ++r) {
            #pragma unroll
            for (int nt = 0; nt < 8; ++nt) {
                const f16x8 afrag = *reinterpret_cast<const f16x8*>(
                    Wt + (((r * FEAT) + nt * 16 + lm) * FEAT + k0));
                acc[r][nt] = __builtin_amdgcn_mfma_f32_16x16x32_f16(
                    afrag, bfrag, acc[r][nt], 0, 0, 0);
            }
        }
    }

    if (grow < N) {
        #pragma unroll
        for (int r = 0; r < 3; ++r) {
            __half* Hr = H + (long)r * plane + (long)grow * FEAT;
            #pragma unroll
            for (int nt = 0; nt < 8; ++nt) {
                __half2 p[2];
                p[0] = __floats2half2_rn(acc[r][nt][0], acc[r][nt][1]);
                p[1] = __floats2half2_rn(acc[r][nt][2], acc[r][nt][3]);
                *reinterpret_cast<uint2*>(Hr + nt * 16 + g * 4) =
                    *reinterpret_cast<const uint2*>(p);
            }
        }
    }
}

// ---------------------------------------------------------------------------
// Gather-aggregate + relu: one wave per dst row.
// out[d,:] = relu( sum_r sum_{e in in_r(d)} H_r[src_e, :] )
// 64 lanes x (1x uint = half2) = one coalesced 256B row per edge.
// ---------------------------------------------------------------------------
__global__ __launch_bounds__(256) void gather_out_kernel(
    const __half* __restrict__ H,
    const int* __restrict__ rs0, const int* __restrict__ es0,
    const int* __restrict__ rs1, const int* __restrict__ es1,
    const int* __restrict__ rs2, const int* __restrict__ es2,
    float* __restrict__ out, int N, long plane)
{
    const int w = blockIdx.x * (blockDim.x >> 6) + (threadIdx.x >> 6);
    if (w >= N) return;
    const int lane = threadIdx.x & 63;
    const int coff = lane * 2;

    float accx = 0.f, accy = 0.f;
    const int* rss[3] = {rs0, rs1, rs2};
    const int* ess[3] = {es0, es1, es2};

    #pragma unroll
    for (int r = 0; r < 3; ++r) {
        const __half* __restrict__ Hr = H + (long)r * plane;
        const int* __restrict__ es = ess[r];
        int j = rss[r][w];
        const int jend = rss[r][w + 1];
        for (; j + 2 <= jend; j += 2) {
            const int s0 = es[j];
            const int s1 = es[j + 1];
            const __half2 a = *reinterpret_cast<const __half2*>(Hr + (long)s0 * FEAT + coff);
            const __half2 b = *reinterpret_cast<const __half2*>(Hr + (long)s1 * FEAT + coff);
            const float2 fa = __half22float2(a);
            const float2 fb = __half22float2(b);
            accx += fa.x + fb.x;
            accy += fa.y + fb.y;
        }
        if (j < jend) {
            const __half2 a = *reinterpret_cast<const __half2*>(Hr + (long)es[j] * FEAT + coff);
            const float2 fa = __half22float2(a);
            accx += fa.x;
            accy += fa.y;
        }
    }

    *reinterpret_cast<float2*>(out + (long)w * FEAT + coff) =
        make_float2(fmaxf(accx, 0.f), fmaxf(accy, 0.f));
}

// ---------------------------------------------------------------------------
// Fallback (round-1) kernels, used only if ws is too small
// ---------------------------------------------------------------------------
__global__ __launch_bounds__(256) void scatter_kernel(
    const float* __restrict__ x, const int* __restrict__ src,
    const int* __restrict__ dst, float* __restrict__ agg, int E)
{
    long tid = (long)blockIdx.x * blockDim.x + threadIdx.x;
    long e = tid >> 5;
    int  c = (int)(tid & 31) << 2;
    if (e >= E) return;
    int s = src[e];
    int d = dst[e];
    const float4 v = *reinterpret_cast<const float4*>(x + (long)s * FEAT + c);
    float* p = agg + (long)d * FEAT + c;
    atomicAdd(p + 0, v.x);
    atomicAdd(p + 1, v.y);
    atomicAdd(p + 2, v.z);
    atomicAdd(p + 3, v.w);
}

__global__ __launch_bounds__(256) void gemm_acc_kernel(
    const float* __restrict__ A, const float* __restrict__ W,
    float* __restrict__ out, int N, int accum, int relu)
{
    __shared__ float As[16][68];
    __shared__ float Bs[16][128];
    const int t = threadIdx.x;
    const int row0 = blockIdx.x * 64;
    const int cg = t & 31;
    const int rg = t >> 5;
    const int arow = t >> 2;
    const int ac4  = (t & 3) << 2;
    float acc[8][4];
    #pragma unroll
    for (int i = 0; i < 8; ++i)
        #pragma unroll
        for (int j = 0; j < 4; ++j) acc[i][j] = 0.f;
    for (int kb = 0; kb < 8; ++kb) {
        float4 va = make_float4(0.f, 0.f, 0.f, 0.f);
        const int grow = row0 + arow;
        if (grow < N)
            va = *reinterpret_cast<const float4*>(A + (long)grow * FEAT + kb * 16 + ac4);
        __syncthreads();
        As[ac4 + 0][arow] = va.x;
        As[ac4 + 1][arow] = va.y;
        As[ac4 + 2][arow] = va.z;
        As[ac4 + 3][arow] = va.w;
        {
            const int bk = t >> 5;
            const int bc = (t & 31) << 2;
            *reinterpret_cast<float4*>(&Bs[bk][bc]) =
                *reinterpret_cast<const float4*>(W + (long)(kb * 16 + bk) * FEAT + bc);
            *reinterpret_cast<float4*>(&Bs[bk + 8][bc]) =
                *reinterpret_cast<const float4*>(W + (long)(kb * 16 + bk + 8) * FEAT + bc);
        }
        __syncthreads();
        #pragma unroll
        for (int k = 0; k < 16; ++k) {
            float a[8];
            #pragma unroll
            for (int i = 0; i < 8; ++i) a[i] = As[k][rg * 8 + i];
            const float4 b = *reinterpret_cast<const float4*>(&Bs[k][cg * 4]);
            #pragma unroll
            for (int i = 0; i < 8; ++i) {
                acc[i][0] += a[i] * b.x;
                acc[i][1] += a[i] * b.y;
                acc[i][2] += a[i] * b.z;
                acc[i][3] += a[i] * b.w;
            }
        }
    }
    #pragma unroll
    for (int i = 0; i < 8; ++i) {
        const int grow = row0 + rg * 8 + i;
        if (grow >= N) continue;
        float* p = out + (long)grow * FEAT + cg * 4;
        float4 o = make_float4(acc[i][0], acc[i][1], acc[i][2], acc[i][3]);
        if (accum) {
            const float4 prev = *reinterpret_cast<const float4*>(p);
            o.x += prev.x; o.y += prev.y; o.z += prev.z; o.w += prev.w;
        }
        if (relu) {
            o.x = fmaxf(o.x, 0.f); o.y = fmaxf(o.y, 0.f);
            o.z = fmaxf(o.z, 0.f); o.w = fmaxf(o.w, 0.f);
        }
        *reinterpret_cast<float4*>(p) = o;
    }
}

// ---------------------------------------------------------------------------
extern "C" void kernel_launch(void* const* d_in, const int* in_sizes, int n_in,
                              void* d_out, int out_size, void* d_ws, size_t ws_size,
                              hipStream_t stream)
{
    const float* x  = (const float*)d_in[0];
    const float* W0 = (const float*)d_in[1];
    const float* W1 = (const float*)d_in[2];
    const float* W2 = (const float*)d_in[3];
    const int* src0 = (const int*)d_in[4];
    const int* dst0 = (const int*)d_in[5];
    const int* src1 = (const int*)d_in[6];
    const int* dst1 = (const int*)d_in[7];
    const int* src2 = (const int*)d_in[8];
    const int* dst2 = (const int*)d_in[9];
    float* out = (float*)d_out;

    const int N  = in_sizes[0] / FEAT;
    const int E0 = in_sizes[4];
    const int E1 = in_sizes[6];
    const int E2 = in_sizes[8];
    const int Emax = max(E0, max(E1, E2));

    const long plane = (long)N * FEAT;
    const int nch = (N + 4095) / 4096;

    // ---- workspace layout ----
    __half* Hh = (__half*)d_ws;                           // 3 * plane halves
    _Float16* Wt = (_Float16*)(Hh + 3 * plane);           // 3*128*128 halves
    int* cnt  = (int*)(Wt + 3 * FEAT * FEAT);             // 3 * N
    int* rs   = cnt + 3 * (size_t)N;                      // 3 * (N+1)
    int* cur  = rs + 3 * (size_t)(N + 1);                 // 3 * N
    int* es   = cur + 3 * (size_t)N;                      // E0+E1+E2
    int* bsum = es + (size_t)E0 + E1 + E2;                // 3 * nch
    const size_t needed = (char*)(bsum + 3 * (size_t)nch) - (char*)d_ws;

    if (ws_size >= needed) {
        // 1) Wt = f16 transpose of W
        convw_kernel<<<(3 * FEAT * FEAT + 255) / 256, 256, 0, stream>>>(W0, W1, W2, Wt);
        // 2) H_r = x @ W_r (f16 MFMA)
        const int mtiles = (N + 15) / 16;
        h3_kernel<<<(mtiles + 3) / 4, 256, 0, stream>>>(x, Wt, Hh, N, plane);
        // 3) CSR build
        hipMemsetAsync(cnt, 0, 3 * (size_t)N * sizeof(int), stream);
        hist3_kernel<<<dim3((Emax + 255) / 256, 3), 256, 0, stream>>>(
            dst0, dst1, dst2, cnt, N, E0, E1, E2);
        chunk_sum_kernel<<<dim3(nch, 3), 256, 0, stream>>>(cnt, bsum, N, nch);
        chunk_scan_kernel<<<1, 64, 0, stream>>>(bsum, rs, N, nch);
        scan_chunk_kernel<<<dim3(nch, 3), 256, 0, stream>>>(cnt, bsum, rs, cur, N, nch);
        int* es0 = es;
        int* es1 = es0 + E0;
        int* es2 = es1 + E1;
        fill3_kernel<<<dim3((Emax + 255) / 256, 3), 256, 0, stream>>>(
            src0, dst0, src1, dst1, src2, dst2, cur, es0, es1, es2, N, E0, E1, E2);
        // 4) gather + relu
        gather_out_kernel<<<(N + 3) / 4, 256, 0, stream>>>(
            Hh, rs, es0, rs + (N + 1), es1, rs + 2 * (N + 1), es2, out, N, plane);
    } else {
        // ---- fallback: sequential scatter + f32 GEMM ----
        float* agg = (float*)d_ws;
        const int* srca[3] = {src0, src1, src2};
        const int* dsta[3] = {dst0, dst1, dst2};
        const float* wa[3] = {W0, W1, W2};
        const int Ea[3] = {E0, E1, E2};
        const int gemm_blocks = (N + 63) / 64;
        for (int r = 0; r < 3; ++r) {
            hipMemsetAsync(d_ws, 0, plane * sizeof(float), stream);
            scatter_kernel<<<((long)Ea[r] * 32 + 255) / 256, 256, 0, stream>>>(
                x, srca[r], dsta[r], agg, Ea[r]);
            gemm_acc_kernel<<<gemm_blocks, 256, 0, stream>>>(
                agg, wa[r], out, N, r > 0, r == 2);
        }
    }
}

// Round 4
// 440.803 us; speedup vs baseline: 7.4465x; 1.2611x over previous
//
#include <hip/hip_runtime.h>
#include <hip/hip_fp16.h>

#define FEAT 128
#define CAP 16
#define OVCAP 65536

typedef _Float16 f16x8 __attribute__((ext_vector_type(8)));
typedef float f32x4 __attribute__((ext_vector_type(4)));

// ---------------------------------------------------------------------------
// W transpose + f32->f16 convert: Wt[r][n][k] = (f16) W_r[k][n]
// ---------------------------------------------------------------------------
__global__ __launch_bounds__(256) void convw_kernel(
    const float* __restrict__ w0, const float* __restrict__ w1,
    const float* __restrict__ w2, _Float16* __restrict__ Wt)
{
    const int idx = blockIdx.x * 256 + threadIdx.x;   // [0, 3*128*128)
    if (idx >= 3 * FEAT * FEAT) return;
    const int r = idx >> 14;
    const int n = (idx >> 7) & 127;
    const int k = idx & 127;
    const float* W = (r == 0) ? w0 : (r == 1) ? w1 : w2;
    Wt[idx] = (_Float16)W[k * FEAT + n];
}

// ---------------------------------------------------------------------------
// Fused build kernel:
//   blocks [0, FB)      : slot-table fill (4 edges/thread, ILP-4 atomics)
//   blocks [FB, FB+HB)  : H_r = x @ W_r  (f16 MFMA, one relation per block)
// Fill blocks are first in the grid so the latency-bound part saturates
// immediately and MFMA blocks backfill the CUs behind it.
// ---------------------------------------------------------------------------
__global__ __launch_bounds__(256) void build_kernel(
    const float* __restrict__ x, const _Float16* __restrict__ Wt,
    __half* __restrict__ H,
    const int* __restrict__ s0, const int* __restrict__ d0,
    const int* __restrict__ s1, const int* __restrict__ d1,
    const int* __restrict__ s2, const int* __restrict__ d2,
    int* __restrict__ cnt, int* __restrict__ slots,
    int2* __restrict__ ovf, int* __restrict__ ovfn,
    int N, long plane, int E0, int E1, int E2,
    int FB0, int FB1, int FB2)
{
    const int b = blockIdx.x;
    const int FB = FB0 + FB1 + FB2;
    if (b < FB) {
        // ---- slot-fill path ----
        int rel, chunk, E;
        const int* src; const int* dst;
        if (b < FB0)            { rel = 0; chunk = b;             src = s0; dst = d0; E = E0; }
        else if (b < FB0 + FB1) { rel = 1; chunk = b - FB0;       src = s1; dst = d1; E = E1; }
        else                    { rel = 2; chunk = b - FB0 - FB1; src = s2; dst = d2; E = E2; }
        const int e0 = (chunk * 256 + threadIdx.x) * 4;
        if (e0 >= E) return;
        int sv[4], dv[4], p[4];
        if (e0 + 3 < E) {
            *reinterpret_cast<int4*>(sv) = *reinterpret_cast<const int4*>(src + e0);
            *reinterpret_cast<int4*>(dv) = *reinterpret_cast<const int4*>(dst + e0);
        } else {
            #pragma unroll
            for (int i = 0; i < 4; ++i) {
                sv[i] = (e0 + i < E) ? src[e0 + i] : 0;
                dv[i] = (e0 + i < E) ? dst[e0 + i] : 0;
            }
        }
        int* crel = cnt + (size_t)rel * N;
        #pragma unroll
        for (int i = 0; i < 4; ++i)
            p[i] = (e0 + i < E) ? atomicAdd(&crel[dv[i]], 1) : 0;
        #pragma unroll
        for (int i = 0; i < 4; ++i) {
            if (e0 + i >= E) continue;
            if (p[i] < CAP)
                slots[((size_t)rel * N + dv[i]) * CAP + p[i]] = sv[i];
            else {
                const int q = atomicAdd(ovfn, 1);
                if (q < OVCAP) ovf[q] = make_int2(dv[i], (rel << 20) | sv[i]);
            }
        }
        return;
    }
    // ---- H-GEMM path: one relation per block, 4 waves x 16-row tiles ----
    const int hb = b - FB;
    const int rel = hb % 3;
    const int tile4 = hb / 3;
    const int t = threadIdx.x;
    const int wv = t >> 6;
    const int l = t & 63;
    const int mtiles = (N + 15) >> 4;
    const int m16 = tile4 * 4 + wv;
    if (m16 >= mtiles) return;
    const int lm = l & 15;        // H row within tile (D col)
    const int g  = l >> 4;        // k-group; D row group = g*4
    const int grow = m16 * 16 + lm;
    const int lrow = (grow < N) ? grow : (N - 1);
    const float* __restrict__ xr = x + (long)lrow * FEAT;
    const _Float16* __restrict__ Wr = Wt + (size_t)rel * FEAT * FEAT;

    f32x4 acc[8];
    #pragma unroll
    for (int nt = 0; nt < 8; ++nt) acc[nt] = 0;

    #pragma unroll
    for (int kq = 0; kq < 4; ++kq) {
        const int k0 = kq * 32 + g * 8;
        const float4 xa = *reinterpret_cast<const float4*>(xr + k0);
        const float4 xb = *reinterpret_cast<const float4*>(xr + k0 + 4);
        f16x8 bfrag;
        bfrag[0] = (_Float16)xa.x; bfrag[1] = (_Float16)xa.y;
        bfrag[2] = (_Float16)xa.z; bfrag[3] = (_Float16)xa.w;
        bfrag[4] = (_Float16)xb.x; bfrag[5] = (_Float16)xb.y;
        bfrag[6] = (_Float16)xb.z; bfrag[7] = (_Float16)xb.w;
        #pragma unroll
        for (int nt = 0; nt < 8; ++nt) {
            const f16x8 afrag = *reinterpret_cast<const f16x8*>(
                Wr + ((nt * 16 + lm) * FEAT + k0));
            acc[nt] = __builtin_amdgcn_mfma_f32_16x16x32_f16(
                afrag, bfrag, acc[nt], 0, 0, 0);
        }
    }

    if (grow < N) {
        __half* Hr = H + (long)rel * plane + (long)grow * FEAT;
        #pragma unroll
        for (int nt = 0; nt < 8; ++nt) {
            __half2 pk[2];
            pk[0] = __floats2half2_rn(acc[nt][0], acc[nt][1]);
            pk[1] = __floats2half2_rn(acc[nt][2], acc[nt][3]);
            *reinterpret_cast<uint2*>(Hr + nt * 16 + g * 4) =
                *reinterpret_cast<const uint2*>(pk);
        }
    }
}

// ---------------------------------------------------------------------------
// Gather-aggregate + relu: one wave per dst row.
// out[d,:] = relu( sum_r sum_{slots of d in rel r} H_r[src, :] )
// 64 lanes x half2 = one coalesced 256B row per edge.
// ---------------------------------------------------------------------------
__global__ __launch_bounds__(256) void gather_out_kernel(
    const __half* __restrict__ H,
    const int* __restrict__ cnt, const int* __restrict__ slots,
    const int2* __restrict__ ovf, const int* __restrict__ ovfn,
    float* __restrict__ out, int N, long plane)
{
    const int w = blockIdx.x * 4 + (threadIdx.x >> 6);
    if (w >= N) return;
    const int lane = threadIdx.x & 63;
    const int coff = lane * 2;

    float accx = 0.f, accy = 0.f;
    bool ovr = false;

    #pragma unroll
    for (int r = 0; r < 3; ++r) {
        const __half* __restrict__ Hr = H + (long)r * plane;
        const int deg = cnt[(size_t)r * N + w];
        const int* __restrict__ sl = slots + ((size_t)r * N + w) * CAP;
        const int dm = (deg < CAP) ? deg : CAP;
        ovr |= (deg > CAP);
        int j = 0;
        for (; j + 2 <= dm; j += 2) {
            const int a0 = sl[j];
            const int a1 = sl[j + 1];
            const __half2 va = *reinterpret_cast<const __half2*>(Hr + (long)a0 * FEAT + coff);
            const __half2 vb = *reinterpret_cast<const __half2*>(Hr + (long)a1 * FEAT + coff);
            const float2 fa = __half22float2(va);
            const float2 fb = __half22float2(vb);
            accx += fa.x + fb.x;
            accy += fa.y + fb.y;
        }
        if (j < dm) {
            const __half2 va = *reinterpret_cast<const __half2*>(Hr + (long)sl[j] * FEAT + coff);
            const float2 fa = __half22float2(va);
            accx += fa.x;
            accy += fa.y;
        }
    }

    if (ovr) {
        const int n = min(*ovfn, OVCAP);
        for (int q = 0; q < n; ++q) {
            const int2 e = ovf[q];
            if (e.x == w) {
                const int r = e.y >> 20;
                const int s = e.y & ((1 << 20) - 1);
                const __half2 va = *reinterpret_cast<const __half2*>(
                    H + (long)r * plane + (long)s * FEAT + coff);
                const float2 fa = __half22float2(va);
                accx += fa.x;
                accy += fa.y;
            }
        }
    }

    *reinterpret_cast<float2*>(out + (long)w * FEAT + coff) =
        make_float2(fmaxf(accx, 0.f), fmaxf(accy, 0.f));
}

// ---------------------------------------------------------------------------
// Fallback (round-1) kernels, used only if ws is too small
// ---------------------------------------------------------------------------
__global__ __launch_bounds__(256) void scatter_kernel(
    const float* __restrict__ x, const int* __restrict__ src,
    const int* __restrict__ dst, float* __restrict__ agg, int E)
{
    long tid = (long)blockIdx.x * blockDim.x + threadIdx.x;
    long e = tid >> 5;
    int  c = (int)(tid & 31) << 2;
    if (e >= E) return;
    int s = src[e];
    int d = dst[e];
    const float4 v = *reinterpret_cast<const float4*>(x + (long)s * FEAT + c);
    float* p = agg + (long)d * FEAT + c;
    atomicAdd(p + 0, v.x);
    atomicAdd(p + 1, v.y);
    atomicAdd(p + 2, v.z);
    atomicAdd(p + 3, v.w);
}

__global__ __launch_bounds__(256) void gemm_acc_kernel(
    const float* __restrict__ A, const float* __restrict__ W,
    float* __restrict__ out, int N, int accum, int relu)
{
    __shared__ float As[16][68];
    __shared__ float Bs[16][128];
    const int t = threadIdx.x;
    const int row0 = blockIdx.x * 64;
    const int cg = t & 31;
    const int rg = t >> 5;
    const int arow = t >> 2;
    const int ac4  = (t & 3) << 2;
    float acc[8][4];
    #pragma unroll
    for (int i = 0; i < 8; ++i)
        #pragma unroll
        for (int j = 0; j < 4; ++j) acc[i][j] = 0.f;
    for (int kb = 0; kb < 8; ++kb) {
        float4 va = make_float4(0.f, 0.f, 0.f, 0.f);
        const int grow = row0 + arow;
        if (grow < N)
            va = *reinterpret_cast<const float4*>(A + (long)grow * FEAT + kb * 16 + ac4);
        __syncthreads();
        As[ac4 + 0][arow] = va.x;
        As[ac4 + 1][arow] = va.y;
        As[ac4 + 2][arow] = va.z;
        As[ac4 + 3][arow] = va.w;
        {
            const int bk = t >> 5;
            const int bc = (t & 31) << 2;
            *reinterpret_cast<float4*>(&Bs[bk][bc]) =
                *reinterpret_cast<const float4*>(W + (long)(kb * 16 + bk) * FEAT + bc);
            *reinterpret_cast<float4*>(&Bs[bk + 8][bc]) =
                *reinterpret_cast<const float4*>(W + (long)(kb * 16 + bk + 8) * FEAT + bc);
        }
        __syncthreads();
        #pragma unroll
        for (int k = 0; k < 16; ++k) {
            float a[8];
            #pragma unroll
            for (int i = 0; i < 8; ++i) a[i] = As[k][rg * 8 + i];
            const float4 b = *reinterpret_cast<const float4*>(&Bs[k][cg * 4]);
            #pragma unroll
            for (int i = 0; i < 8; ++i) {
                acc[i][0] += a[i] * b.x;
                acc[i][1] += a[i] * b.y;
                acc[i][2] += a[i] * b.z;
                acc[i][3] += a[i] * b.w;
            }
        }
    }
    #pragma unroll
    for (int i = 0; i < 8; ++i) {
        const int grow = row0 + rg * 8 + i;
        if (grow >= N) continue;
        float* p = out + (long)grow * FEAT + cg * 4;
        float4 o = make_float4(acc[i][0], acc[i][1], acc[i][2], acc[i][3]);
        if (accum) {
            const float4 prev = *reinterpret_cast<const float4*>(p);
            o.x += prev.x; o.y += prev.y; o.z += prev.z; o.w += prev.w;
        }
        if (relu) {
            o.x = fmaxf(o.x, 0.f); o.y = fmaxf(o.y, 0.f);
            o.z = fmaxf(o.z, 0.f); o.w = fmaxf(o.w, 0.f);
        }
        *reinterpret_cast<float4*>(p) = o;
    }
}

// ---------------------------------------------------------------------------
extern "C" void kernel_launch(void* const* d_in, const int* in_sizes, int n_in,
                              void* d_out, int out_size, void* d_ws, size_t ws_size,
                              hipStream_t stream)
{
    const float* x  = (const float*)d_in[0];
    const float* W0 = (const float*)d_in[1];
    const float* W1 = (const float*)d_in[2];
    const float* W2 = (const float*)d_in[3];
    const int* src0 = (const int*)d_in[4];
    const int* dst0 = (const int*)d_in[5];
    const int* src1 = (const int*)d_in[6];
    const int* dst1 = (const int*)d_in[7];
    const int* src2 = (const int*)d_in[8];
    const int* dst2 = (const int*)d_in[9];
    float* out = (float*)d_out;

    const int N  = in_sizes[0] / FEAT;
    const int E0 = in_sizes[4];
    const int E1 = in_sizes[6];
    const int E2 = in_sizes[8];

    const long plane = (long)N * FEAT;

    // ---- workspace layout ----
    __half* Hh   = (__half*)d_ws;                        // 3 * plane halves
    _Float16* Wt = (_Float16*)(Hh + 3 * plane);          // 3*128*128 halves
    int* cnt   = (int*)(Wt + 3 * FEAT * FEAT);           // 3*N
    int* ovfn  = cnt + 3 * (size_t)N;                    // 1 (+1 pad)
    int* slots = ovfn + 2;                               // 3*N*CAP
    char* ovf_raw = (char*)(slots + 3 * (size_t)N * CAP);
    int2* ovf = (int2*)(((uintptr_t)ovf_raw + 7) & ~(uintptr_t)7);
    const size_t needed = (char*)(ovf + OVCAP) - (char*)d_ws;

    if (ws_size >= needed) {
        // 1) Wt = f16 transpose of W
        convw_kernel<<<(3 * FEAT * FEAT + 255) / 256, 256, 0, stream>>>(W0, W1, W2, Wt);
        // 2) zero counters (+ overflow cursor)
        hipMemsetAsync(cnt, 0, (3 * (size_t)N + 2) * sizeof(int), stream);
        // 3) fused slot-fill + H-GEMM
        const int FB0 = (E0 + 1023) / 1024;
        const int FB1 = (E1 + 1023) / 1024;
        const int FB2 = (E2 + 1023) / 1024;
        const int mtiles = (N + 15) / 16;
        const int HB = 3 * ((mtiles + 3) / 4);
        build_kernel<<<FB0 + FB1 + FB2 + HB, 256, 0, stream>>>(
            x, Wt, Hh, src0, dst0, src1, dst1, src2, dst2,
            cnt, slots, ovf, ovfn, N, plane, E0, E1, E2, FB0, FB1, FB2);
        // 4) gather + relu
        gather_out_kernel<<<(N + 3) / 4, 256, 0, stream>>>(
            Hh, cnt, slots, ovf, ovfn, out, N, plane);
    } else {
        // ---- fallback: sequential scatter + f32 GEMM ----
        float* agg = (float*)d_ws;
        const int* srca[3] = {src0, src1, src2};
        const int* dsta[3] = {dst0, dst1, dst2};
        const float* wa[3] = {W0, W1, W2};
        const int Ea[3] = {E0, E1, E2};
        const int gemm_blocks = (N + 63) / 64;
        for (int r = 0; r < 3; ++r) {
            hipMemsetAsync(d_ws, 0, plane * sizeof(float), stream);
            scatter_kernel<<<((long)Ea[r] * 32 + 255) / 256, 256, 0, stream>>>(
                x, srca[r], dsta[r], agg, Ea[r]);
            gemm_acc_kernel<<<gemm_blocks, 256, 0, stream>>>(
                agg, wa[r], out, N, r > 0, r == 2);
        }
    }
}

// Round 5
// 432.024 us; speedup vs baseline: 7.5978x; 1.0203x over previous
//
#include <hip/hip_runtime.h>
#include <hip/hip_fp16.h>

#define FEAT 128
#define CAP 16
#define OVCAP 65536

typedef _Float16 f16x8 __attribute__((ext_vector_type(8)));
typedef float f32x4 __attribute__((ext_vector_type(4)));

// ---------------------------------------------------------------------------
// W transpose + f32->f16 convert: Wt[r][n][k] = (f16) W_r[k][n]
// ---------------------------------------------------------------------------
__global__ __launch_bounds__(256) void convw_kernel(
    const float* __restrict__ w0, const float* __restrict__ w1,
    const float* __restrict__ w2, _Float16* __restrict__ Wt)
{
    const int idx = blockIdx.x * 256 + threadIdx.x;   // [0, 3*128*128)
    if (idx >= 3 * FEAT * FEAT) return;
    const int r = idx >> 14;
    const int n = (idx >> 7) & 127;
    const int k = idx & 127;
    const float* W = (r == 0) ? w0 : (r == 1) ? w1 : w2;
    Wt[idx] = (_Float16)W[k * FEAT + n];
}

// ---------------------------------------------------------------------------
// H_r = x @ W_r for r=0..2 (f16 MFMA, operand-swapped).  3 relations per
// block so x rows are loaded once.  Lane holds H row m=lane&15,
// cols n = (lane>>4)*4 + reg of tile nt.
// ---------------------------------------------------------------------------
__global__ __launch_bounds__(256) void h3_kernel(
    const float* __restrict__ x, const _Float16* __restrict__ Wt,
    __half* __restrict__ H, int N, long plane)
{
    const int t = threadIdx.x;
    const int wv = t >> 6;
    const int l = t & 63;
    const int mtiles = (N + 15) >> 4;
    const int m16 = blockIdx.x * 4 + wv;
    if (m16 >= mtiles) return;
    const int lm = l & 15;
    const int g  = l >> 4;
    const int grow = m16 * 16 + lm;
    const int lrow = (grow < N) ? grow : (N - 1);
    const float* __restrict__ xr = x + (long)lrow * FEAT;

    f32x4 acc[3][8];
    #pragma unroll
    for (int r = 0; r < 3; ++r)
        #pragma unroll
        for (int nt = 0; nt < 8; ++nt)
            acc[r][nt] = 0;

    #pragma unroll
    for (int kq = 0; kq < 4; ++kq) {
        const int k0 = kq * 32 + g * 8;
        const float4 xa = *reinterpret_cast<const float4*>(xr + k0);
        const float4 xb = *reinterpret_cast<const float4*>(xr + k0 + 4);
        f16x8 bfrag;
        bfrag[0] = (_Float16)xa.x; bfrag[1] = (_Float16)xa.y;
        bfrag[2] = (_Float16)xa.z; bfrag[3] = (_Float16)xa.w;
        bfrag[4] = (_Float16)xb.x; bfrag[5] = (_Float16)xb.y;
        bfrag[6] = (_Float16)xb.z; bfrag[7] = (_Float16)xb.w;
        #pragma unroll
        for (int r = 0; r < 3; ++r) {
            #pragma unroll
            for (int nt = 0; nt < 8; ++nt) {
                const f16x8 afrag = *reinterpret_cast<const f16x8*>(
                    Wt + (((r * FEAT) + nt * 16 + lm) * FEAT + k0));
                acc[r][nt] = __builtin_amdgcn_mfma_f32_16x16x32_f16(
                    afrag, bfrag, acc[r][nt], 0, 0, 0);
            }
        }
    }

    if (grow < N) {
        #pragma unroll
        for (int r = 0; r < 3; ++r) {
            __half* Hr = H + (long)r * plane + (long)grow * FEAT;
            #pragma unroll
            for (int nt = 0; nt < 8; ++nt) {
                __half2 pk[2];
                pk[0] = __floats2half2_rn(acc[r][nt][0], acc[r][nt][1]);
                pk[1] = __floats2half2_rn(acc[r][nt][2], acc[r][nt][3]);
                *reinterpret_cast<uint2*>(Hr + nt * 16 + g * 4) =
                    *reinterpret_cast<const uint2*>(pk);
            }
        }
    }
}

// ---------------------------------------------------------------------------
// Slot-table fill, 8 edges/thread (8 independent atomic->store chains).
// slots[(rel*N + d)*CAP + p] = src ; overflow (deg>CAP) to tagged list.
// ---------------------------------------------------------------------------
__global__ __launch_bounds__(256) void fill8_kernel(
    const int* __restrict__ s0, const int* __restrict__ d0,
    const int* __restrict__ s1, const int* __restrict__ d1,
    const int* __restrict__ s2, const int* __restrict__ d2,
    int* __restrict__ cnt, int* __restrict__ slots,
    int2* __restrict__ ovf, int* __restrict__ ovfn,
    int N, int E0, int E1, int E2, int FB0, int FB1, int FB2)
{
    const int b = blockIdx.x;
    int rel, chunk, E;
    const int* src; const int* dst;
    if (b < FB0)            { rel = 0; chunk = b;             src = s0; dst = d0; E = E0; }
    else if (b < FB0 + FB1) { rel = 1; chunk = b - FB0;       src = s1; dst = d1; E = E1; }
    else                    { rel = 2; chunk = b - FB0 - FB1; src = s2; dst = d2; E = E2; }

    const int e0 = (chunk * 256 + threadIdx.x) * 8;
    if (e0 >= E) return;
    int sv[8], dv[8], p[8];
    if (e0 + 7 < E) {
        *reinterpret_cast<int4*>(sv)     = *reinterpret_cast<const int4*>(src + e0);
        *reinterpret_cast<int4*>(sv + 4) = *reinterpret_cast<const int4*>(src + e0 + 4);
        *reinterpret_cast<int4*>(dv)     = *reinterpret_cast<const int4*>(dst + e0);
        *reinterpret_cast<int4*>(dv + 4) = *reinterpret_cast<const int4*>(dst + e0 + 4);
    } else {
        #pragma unroll
        for (int i = 0; i < 8; ++i) {
            sv[i] = (e0 + i < E) ? src[e0 + i] : 0;
            dv[i] = (e0 + i < E) ? dst[e0 + i] : 0;
        }
    }
    int* crel = cnt + (size_t)rel * N;
    #pragma unroll
    for (int i = 0; i < 8; ++i)
        p[i] = (e0 + i < E) ? atomicAdd(&crel[dv[i]], 1) : CAP;
    #pragma unroll
    for (int i = 0; i < 8; ++i) {
        if (e0 + i >= E) continue;
        if (p[i] < CAP)
            slots[((size_t)rel * N + dv[i]) * CAP + p[i]] = sv[i];
        else {
            const int q = atomicAdd(ovfn, 1);
            if (q < OVCAP) ovf[q] = make_int2(dv[i], (rel << 20) | sv[i]);
        }
    }
}

// ---------------------------------------------------------------------------
// Gather-aggregate + relu: one wave per dst row, half-wave edge pairing.
// Lanes 0-31 process edge j, lanes 32-63 edge j+1; each lane loads 8B
// (4 halves) of the 256B H row.  Slot line preloaded + distributed by shfl.
// One cross-half merge at the end; lanes 0-31 store float4 (512B row).
// ---------------------------------------------------------------------------
__global__ __launch_bounds__(256) void gather_out_kernel(
    const __half* __restrict__ H,
    const int* __restrict__ cnt, const int* __restrict__ slots,
    const int2* __restrict__ ovf, const int* __restrict__ ovfn,
    float* __restrict__ out, int N, long plane)
{
    const int w = blockIdx.x * 4 + (threadIdx.x >> 6);
    if (w >= N) return;
    const int lane = threadIdx.x & 63;
    const int hi = lane >> 5;          // half-wave id
    const int c4 = (lane & 31) * 4;    // this lane's 4 columns

    // degrees for all 3 relations (independent loads, issued together)
    int deg[3];
    #pragma unroll
    for (int r = 0; r < 3; ++r) deg[r] = cnt[(size_t)r * N + w];

    float4 acc = make_float4(0.f, 0.f, 0.f, 0.f);
    bool ovr = false;

    #pragma unroll
    for (int r = 0; r < 3; ++r) {
        const __half* __restrict__ Hr = H + (long)r * plane;
        const int* __restrict__ sl = slots + ((size_t)r * N + w) * CAP;
        const int dm = (deg[r] < CAP) ? deg[r] : CAP;
        ovr |= (deg[r] > CAP);
        if (dm == 0) continue;
        const int slv = sl[lane & 15];       // whole slot line in registers

        int j = 0;
        for (; j + 4 <= dm; j += 4) {        // 4 edges in flight
            const int sA = __shfl(slv, j + hi);
            const int sB = __shfl(slv, j + 2 + hi);
            const uint2 ua = *reinterpret_cast<const uint2*>(Hr + (long)sA * FEAT + c4);
            const uint2 ub = *reinterpret_cast<const uint2*>(Hr + (long)sB * FEAT + c4);
            const float2 a01 = __half22float2(*reinterpret_cast<const __half2*>(&ua.x));
            const float2 a23 = __half22float2(*reinterpret_cast<const __half2*>(&ua.y));
            const float2 b01 = __half22float2(*reinterpret_cast<const __half2*>(&ub.x));
            const float2 b23 = __half22float2(*reinterpret_cast<const __half2*>(&ub.y));
            acc.x += a01.x + b01.x;
            acc.y += a01.y + b01.y;
            acc.z += a23.x + b23.x;
            acc.w += a23.y + b23.y;
        }
        for (; j < dm; j += 2) {             // 0..3 remainder, act-guarded
            const int idx = j + hi;
            const bool act = idx < dm;
            const int s = __shfl(slv, act ? idx : j);
            const uint2 u = *reinterpret_cast<const uint2*>(Hr + (long)s * FEAT + c4);
            const float2 f01 = __half22float2(*reinterpret_cast<const __half2*>(&u.x));
            const float2 f23 = __half22float2(*reinterpret_cast<const __half2*>(&u.y));
            if (act) {
                acc.x += f01.x; acc.y += f01.y;
                acc.z += f23.x; acc.w += f23.y;
            }
        }
    }

    if (ovr && hi == 0) {                    // rare; lo half only (pre-merge)
        const int n = min(*ovfn, OVCAP);
        for (int q = 0; q < n; ++q) {
            const int2 e = ovf[q];
            if (e.x == w) {
                const int r = e.y >> 20;
                const int s = e.y & ((1 << 20) - 1);
                const uint2 u = *reinterpret_cast<const uint2*>(
                    H + (long)r * plane + (long)s * FEAT + c4);
                const float2 f01 = __half22float2(*reinterpret_cast<const __half2*>(&u.x));
                const float2 f23 = __half22float2(*reinterpret_cast<const __half2*>(&u.y));
                acc.x += f01.x; acc.y += f01.y;
                acc.z += f23.x; acc.w += f23.y;
            }
        }
    }

    // merge hi half into lo half
    acc.x += __shfl_xor(acc.x, 32);
    acc.y += __shfl_xor(acc.y, 32);
    acc.z += __shfl_xor(acc.z, 32);
    acc.w += __shfl_xor(acc.w, 32);

    if (hi == 0) {
        const float4 o = make_float4(fmaxf(acc.x, 0.f), fmaxf(acc.y, 0.f),
                                     fmaxf(acc.z, 0.f), fmaxf(acc.w, 0.f));
        *reinterpret_cast<float4*>(out + (long)w * FEAT + c4) = o;
    }
}

// ---------------------------------------------------------------------------
// Fallback (round-1) kernels, used only if ws is too small
// ---------------------------------------------------------------------------
__global__ __launch_bounds__(256) void scatter_kernel(
    const float* __restrict__ x, const int* __restrict__ src,
    const int* __restrict__ dst, float* __restrict__ agg, int E)
{
    long tid = (long)blockIdx.x * blockDim.x + threadIdx.x;
    long e = tid >> 5;
    int  c = (int)(tid & 31) << 2;
    if (e >= E) return;
    int s = src[e];
    int d = dst[e];
    const float4 v = *reinterpret_cast<const float4*>(x + (long)s * FEAT + c);
    float* p = agg + (long)d * FEAT + c;
    atomicAdd(p + 0, v.x);
    atomicAdd(p + 1, v.y);
    atomicAdd(p + 2, v.z);
    atomicAdd(p + 3, v.w);
}

__global__ __launch_bounds__(256) void gemm_acc_kernel(
    const float* __restrict__ A, const float* __restrict__ W,
    float* __restrict__ out, int N, int accum, int relu)
{
    __shared__ float As[16][68];
    __shared__ float Bs[16][128];
    const int t = threadIdx.x;
    const int row0 = blockIdx.x * 64;
    const int cg = t & 31;
    const int rg = t >> 5;
    const int arow = t >> 2;
    const int ac4  = (t & 3) << 2;
    float acc[8][4];
    #pragma unroll
    for (int i = 0; i < 8; ++i)
        #pragma unroll
        for (int j = 0; j < 4; ++j) acc[i][j] = 0.f;
    for (int kb = 0; kb < 8; ++kb) {
        float4 va = make_float4(0.f, 0.f, 0.f, 0.f);
        const int grow = row0 + arow;
        if (grow < N)
            va = *reinterpret_cast<const float4*>(A + (long)grow * FEAT + kb * 16 + ac4);
        __syncthreads();
        As[ac4 + 0][arow] = va.x;
        As[ac4 + 1][arow] = va.y;
        As[ac4 + 2][arow] = va.z;
        As[ac4 + 3][arow] = va.w;
        {
            const int bk = t >> 5;
            const int bc = (t & 31) << 2;
            *reinterpret_cast<float4*>(&Bs[bk][bc]) =
                *reinterpret_cast<const float4*>(W + (long)(kb * 16 + bk) * FEAT + bc);
            *reinterpret_cast<float4*>(&Bs[bk + 8][bc]) =
                *reinterpret_cast<const float4*>(W + (long)(kb * 16 + bk + 8) * FEAT + bc);
        }
        __syncthreads();
        #pragma unroll
        for (int k = 0; k < 16; ++k) {
            float a[8];
            #pragma unroll
            for (int i = 0; i < 8; ++i) a[i] = As[k][rg * 8 + i];
            const float4 b = *reinterpret_cast<const float4*>(&Bs[k][cg * 4]);
            #pragma unroll
            for (int i = 0; i < 8; ++i) {
                acc[i][0] += a[i] * b.x;
                acc[i][1] += a[i] * b.y;
                acc[i][2] += a[i] * b.z;
                acc[i][3] += a[i] * b.w;
            }
        }
    }
    #pragma unroll
    for (int i = 0; i < 8; ++i) {
        const int grow = row0 + rg * 8 + i;
        if (grow >= N) continue;
        float* p = out + (long)grow * FEAT + cg * 4;
        float4 o = make_float4(acc[i][0], acc[i][1], acc[i][2], acc[i][3]);
        if (accum) {
            const float4 prev = *reinterpret_cast<const float4*>(p);
            o.x += prev.x; o.y += prev.y; o.z += prev.z; o.w += prev.w;
        }
        if (relu) {
            o.x = fmaxf(o.x, 0.f); o.y = fmaxf(o.y, 0.f);
            o.z = fmaxf(o.z, 0.f); o.w = fmaxf(o.w, 0.f);
        }
        *reinterpret_cast<float4*>(p) = o;
    }
}

// ---------------------------------------------------------------------------
extern "C" void kernel_launch(void* const* d_in, const int* in_sizes, int n_in,
                              void* d_out, int out_size, void* d_ws, size_t ws_size,
                              hipStream_t stream)
{
    const float* x  = (const float*)d_in[0];
    const float* W0 = (const float*)d_in[1];
    const float* W1 = (const float*)d_in[2];
    const float* W2 = (const float*)d_in[3];
    const int* src0 = (const int*)d_in[4];
    const int* dst0 = (const int*)d_in[5];
    const int* src1 = (const int*)d_in[6];
    const int* dst1 = (const int*)d_in[7];
    const int* src2 = (const int*)d_in[8];
    const int* dst2 = (const int*)d_in[9];
    float* out = (float*)d_out;

    const int N  = in_sizes[0] / FEAT;
    const int E0 = in_sizes[4];
    const int E1 = in_sizes[6];
    const int E2 = in_sizes[8];

    const long plane = (long)N * FEAT;

    // ---- workspace layout ----
    __half* Hh   = (__half*)d_ws;                        // 3 * plane halves
    _Float16* Wt = (_Float16*)(Hh + 3 * plane);          // 3*128*128 halves
    int* cnt   = (int*)(Wt + 3 * FEAT * FEAT);           // 3*N
    int* ovfn  = cnt + 3 * (size_t)N;                    // 1 (+1 pad)
    int* slots = ovfn + 2;                               // 3*N*CAP
    char* ovf_raw = (char*)(slots + 3 * (size_t)N * CAP);
    int2* ovf = (int2*)(((uintptr_t)ovf_raw + 7) & ~(uintptr_t)7);
    const size_t needed = (char*)(ovf + OVCAP) - (char*)d_ws;

    if (ws_size >= needed) {
        // 1) Wt = f16 transpose of W
        convw_kernel<<<(3 * FEAT * FEAT + 255) / 256, 256, 0, stream>>>(W0, W1, W2, Wt);
        // 2) zero counters + overflow cursor
        hipMemsetAsync(cnt, 0, (3 * (size_t)N + 2) * sizeof(int), stream);
        // 3) H-GEMM (standalone)
        const int mtiles = (N + 15) / 16;
        h3_kernel<<<(mtiles + 3) / 4, 256, 0, stream>>>(x, Wt, Hh, N, plane);
        // 4) slot fill (standalone, ILP-8)
        const int FB0 = (E0 + 2047) / 2048;
        const int FB1 = (E1 + 2047) / 2048;
        const int FB2 = (E2 + 2047) / 2048;
        fill8_kernel<<<FB0 + FB1 + FB2, 256, 0, stream>>>(
            src0, dst0, src1, dst1, src2, dst2,
            cnt, slots, ovf, ovfn, N, E0, E1, E2, FB0, FB1, FB2);
        // 5) gather + relu
        gather_out_kernel<<<(N + 3) / 4, 256, 0, stream>>>(
            Hh, cnt, slots, ovf, ovfn, out, N, plane);
    } else {
        // ---- fallback: sequential scatter + f32 GEMM ----
        float* agg = (float*)d_ws;
        const int* srca[3] = {src0, src1, src2};
        const int* dsta[3] = {dst0, dst1, dst2};
        const float* wa[3] = {W0, W1, W2};
        const int Ea[3] = {E0, E1, E2};
        const int gemm_blocks = (N + 63) / 64;
        for (int r = 0; r < 3; ++r) {
            hipMemsetAsync(d_ws, 0, plane * sizeof(float), stream);
            scatter_kernel<<<((long)Ea[r] * 32 + 255) / 256, 256, 0, stream>>>(
                x, srca[r], dsta[r], agg, Ea[r]);
            gemm_acc_kernel<<<gemm_blocks, 256, 0, stream>>>(
                agg, wa[r], out, N, r > 0, r == 2);
        }
    }
}

// Round 6
// 273.278 us; speedup vs baseline: 12.0113x; 1.5809x over previous
//
#include <hip/hip_runtime.h>
#include <hip/hip_fp16.h>

#define FEAT 128
#define CAP 16
#define OVCAP 65536
#define NBUK_MAX 1024

typedef _Float16 f16x8 __attribute__((ext_vector_type(8)));
typedef _Float16 f16x4 __attribute__((ext_vector_type(4)));
typedef float f32x4 __attribute__((ext_vector_type(4)));

// ---------------------------------------------------------------------------
// W transpose + f32->f16 convert: Wt[r][n][k] = (f16) W_r[k][n]
// ---------------------------------------------------------------------------
__global__ __launch_bounds__(256) void convw_kernel(
    const float* __restrict__ w0, const float* __restrict__ w1,
    const float* __restrict__ w2, _Float16* __restrict__ Wt)
{
    const int idx = blockIdx.x * 256 + threadIdx.x;   // [0, 3*128*128)
    if (idx >= 3 * FEAT * FEAT) return;
    const int r = idx >> 14;
    const int n = (idx >> 7) & 127;
    const int k = idx & 127;
    const float* W = (r == 0) ? w0 : (r == 1) ? w1 : w2;
    Wt[idx] = (_Float16)W[k * FEAT + n];
}

// ---------------------------------------------------------------------------
// H_r = x @ W_r, f16 MFMA, operand-swapped (A = W-frag so each lane's C/D
// fragment is 4 consecutive cols of one H row).
// Block: 384 threads = 6 waves = 3 relations x 2 col-halves; 128 rows/block.
// x staged once to LDS (f16, +16B row pad -> conflict-free ds_read_b128);
// W fragments held in registers for the whole block (16 loads/wave total).
// Per wave: 128 MFMA, 32 ds_read, 32 stores.
// ---------------------------------------------------------------------------
__global__ __launch_bounds__(384) void h3_kernel(
    const float* __restrict__ x, const _Float16* __restrict__ Wt,
    __half* __restrict__ H, int N, long plane)
{
    __shared__ _Float16 xs[128][136];   // 34.8 KB, stride 272B
    const int t = threadIdx.x;
    const int row0 = blockIdx.x * 128;

    // stage x[row0..row0+127][0..127] -> f16 LDS (clamped rows)
    for (int idx = t; idx < 4096; idx += 384) {
        const int row = idx >> 5;
        const int c4 = (idx & 31) * 4;
        int gr = row0 + row;
        if (gr >= N) gr = N - 1;
        const float4 v = *reinterpret_cast<const float4*>(x + (long)gr * FEAT + c4);
        f16x4 h4;
        h4[0] = (_Float16)v.x; h4[1] = (_Float16)v.y;
        h4[2] = (_Float16)v.z; h4[3] = (_Float16)v.w;
        *reinterpret_cast<f16x4*>(&xs[row][c4]) = h4;
    }
    __syncthreads();

    const int wv = t >> 6;            // 0..5
    const int l = t & 63;
    const int lm = l & 15;            // H row within 16-tile
    const int g = l >> 4;             // k-group
    const int rel = wv >> 1;
    const int ch = wv & 1;            // col half: cols [ch*64, ch*64+64)

    // A-frags (W) in registers: 4 n-tiles x 4 k-quads, 16B each
    f16x8 af[4][4];
    #pragma unroll
    for (int nt = 0; nt < 4; ++nt)
        #pragma unroll
        for (int kq = 0; kq < 4; ++kq)
            af[nt][kq] = *reinterpret_cast<const f16x8*>(
                Wt + ((size_t)rel * FEAT + ch * 64 + nt * 16 + lm) * FEAT
                   + kq * 32 + g * 8);

    __half* __restrict__ Hrel = H + (long)rel * plane + ch * 64;

    #pragma unroll
    for (int mt = 0; mt < 8; ++mt) {
        f16x8 bf[4];
        #pragma unroll
        for (int kq = 0; kq < 4; ++kq)
            bf[kq] = *reinterpret_cast<const f16x8*>(
                &xs[mt * 16 + lm][kq * 32 + g * 8]);
        f32x4 acc[4];
        #pragma unroll
        for (int nt = 0; nt < 4; ++nt) acc[nt] = 0;
        #pragma unroll
        for (int kq = 0; kq < 4; ++kq)
            #pragma unroll
            for (int nt = 0; nt < 4; ++nt)
                acc[nt] = __builtin_amdgcn_mfma_f32_16x16x32_f16(
                    af[nt][kq], bf[kq], acc[nt], 0, 0, 0);
        const int grow = row0 + mt * 16 + lm;
        if (grow < N) {
            __half* Hr = Hrel + (long)grow * FEAT;
            #pragma unroll
            for (int nt = 0; nt < 4; ++nt) {
                __half2 pk[2];
                pk[0] = __floats2half2_rn(acc[nt][0], acc[nt][1]);
                pk[1] = __floats2half2_rn(acc[nt][2], acc[nt][3]);
                *reinterpret_cast<uint2*>(Hr + nt * 16 + g * 4) =
                    *reinterpret_cast<const uint2*>(pk);
            }
        }
    }
}

// ---------------------------------------------------------------------------
// P1: bucket (dst>>7) histogram.  LDS counts, one global atomic per
// (block,bucket).  512 threads x 16 edges = 8192 edges/block.
// ---------------------------------------------------------------------------
__global__ __launch_bounds__(512) void p1_kernel(
    const int* __restrict__ d0, const int* __restrict__ d1,
    const int* __restrict__ d2, int* __restrict__ bucketCnt, int nbuk,
    int E0, int E1, int E2, int FB0, int FB1, int FB2)
{
    __shared__ int lcnt[NBUK_MAX];
    const int b = blockIdx.x;
    int rel, chunk, E; const int* dst;
    if (b < FB0)            { rel = 0; chunk = b;             dst = d0; E = E0; }
    else if (b < FB0 + FB1) { rel = 1; chunk = b - FB0;       dst = d1; E = E1; }
    else                    { rel = 2; chunk = b - FB0 - FB1; dst = d2; E = E2; }
    const int t = threadIdx.x;
    for (int i = t; i < nbuk; i += 512) lcnt[i] = 0;
    __syncthreads();
    const int e0 = (chunk * 512 + t) * 16;
    int nl = E - e0; nl = nl < 0 ? 0 : (nl > 16 ? 16 : nl);
    int dv[16];
    if (nl == 16) {
        #pragma unroll
        for (int k = 0; k < 4; ++k)
            *reinterpret_cast<int4*>(dv + 4 * k) =
                *reinterpret_cast<const int4*>(dst + e0 + 4 * k);
    } else {
        #pragma unroll
        for (int i = 0; i < 16; ++i) dv[i] = (i < nl) ? dst[e0 + i] : 0;
    }
    #pragma unroll
    for (int i = 0; i < 16; ++i)
        if (i < nl) atomicAdd(&lcnt[dv[i] >> 7], 1);
    __syncthreads();
    for (int i = t; i < nbuk; i += 512)
        if (lcnt[i]) atomicAdd(&bucketCnt[rel * nbuk + i], lcnt[i]);
}

// ---------------------------------------------------------------------------
// Scan of 3*nbuk bucket counts (single block, 256 x 16 = 4096 capacity).
// Writes bucketBase (begin, for P3) and cursor (mutable, for P2).
// ---------------------------------------------------------------------------
__global__ __launch_bounds__(256) void scan_kernel(
    const int* __restrict__ in, int* __restrict__ base,
    int* __restrict__ cur, int n)
{
    const int t = threadIdx.x;
    int v[16];
    int s = 0;
    #pragma unroll
    for (int i = 0; i < 16; ++i) {
        const int idx = t * 16 + i;
        const int x_ = (idx < n) ? in[idx] : 0;
        v[i] = s; s += x_;
    }
    const int lane = t & 63, wv = t >> 6;
    int ps = s;
    #pragma unroll
    for (int o = 1; o < 64; o <<= 1) {
        const int u = __shfl_up(ps, o);
        if (lane >= o) ps += u;
    }
    __shared__ int wtot[4];
    if (lane == 63) wtot[wv] = ps;
    __syncthreads();
    int woff = 0;
    #pragma unroll
    for (int k = 0; k < 4; ++k) if (k < wv) woff += wtot[k];
    const int excl = woff + ps - s;
    #pragma unroll
    for (int i = 0; i < 16; ++i) {
        const int idx = t * 16 + i;
        if (idx < n) { base[idx] = excl + v[i]; cur[idx] = excl + v[i]; }
    }
}

// ---------------------------------------------------------------------------
// P2: partition edges into bucket regions.  Per-edge LDS atomic for local
// rank, ONE global atomic per (block,bucket) to reserve the range, then
// scatter packed words ((dst&127)<<17 | src) -> runs of ~10 contiguous
// entries per block-bucket (low write amplification).
// ---------------------------------------------------------------------------
__global__ __launch_bounds__(512) void p2_kernel(
    const int* __restrict__ s0, const int* __restrict__ d0,
    const int* __restrict__ s1, const int* __restrict__ d1,
    const int* __restrict__ s2, const int* __restrict__ d2,
    int* __restrict__ cursor, unsigned* __restrict__ part, int nbuk,
    int E0, int E1, int E2, int FB0, int FB1, int FB2)
{
    __shared__ int lcnt[NBUK_MAX];
    __shared__ int sbase[NBUK_MAX];
    const int b = blockIdx.x;
    int rel, chunk, E; const int* src; const int* dst;
    if (b < FB0)            { rel = 0; chunk = b;             src = s0; dst = d0; E = E0; }
    else if (b < FB0 + FB1) { rel = 1; chunk = b - FB0;       src = s1; dst = d1; E = E1; }
    else                    { rel = 2; chunk = b - FB0 - FB1; src = s2; dst = d2; E = E2; }
    const int t = threadIdx.x;
    for (int i = t; i < nbuk; i += 512) lcnt[i] = 0;
    __syncthreads();
    const int e0 = (chunk * 512 + t) * 16;
    int nl = E - e0; nl = nl < 0 ? 0 : (nl > 16 ? 16 : nl);
    int sv[16], dv[16], p[16];
    if (nl == 16) {
        #pragma unroll
        for (int k = 0; k < 4; ++k) {
            *reinterpret_cast<int4*>(sv + 4 * k) =
                *reinterpret_cast<const int4*>(src + e0 + 4 * k);
            *reinterpret_cast<int4*>(dv + 4 * k) =
                *reinterpret_cast<const int4*>(dst + e0 + 4 * k);
        }
    } else {
        #pragma unroll
        for (int i = 0; i < 16; ++i) {
            sv[i] = (i < nl) ? src[e0 + i] : 0;
            dv[i] = (i < nl) ? dst[e0 + i] : 0;
        }
    }
    #pragma unroll
    for (int i = 0; i < 16; ++i)
        if (i < nl) p[i] = atomicAdd(&lcnt[dv[i] >> 7], 1);
    __syncthreads();
    for (int i = t; i < nbuk; i += 512) {
        const int c = lcnt[i];
        sbase[i] = c ? atomicAdd(&cursor[rel * nbuk + i], c) : 0;
    }
    __syncthreads();
    #pragma unroll
    for (int i = 0; i < 16; ++i)
        if (i < nl) {
            const int bu = dv[i] >> 7;
            part[sbase[bu] + p[i]] =
                ((unsigned)(dv[i] & 127) << 17) | (unsigned)sv[i];
        }
}

// ---------------------------------------------------------------------------
// P3: one block per (rel,bucket).  LDS counting sort of the bucket's edges,
// then fully-coalesced writes of the 128x16 slot image and the 128 counts.
// No global memset of cnt/slots needed.
// ---------------------------------------------------------------------------
__global__ __launch_bounds__(256) void p3_kernel(
    const unsigned* __restrict__ part, const int* __restrict__ base,
    const int* __restrict__ endp, int* __restrict__ cnt,
    int* __restrict__ slots, int2* __restrict__ ovf, int* __restrict__ ovfn,
    int N, int nbuk)
{
    __shared__ int cnt2[128];
    __shared__ __align__(16) int img[128 * CAP];
    const int gb = blockIdx.x;
    const int rel = gb / nbuk, buck = gb % nbuk;
    const int t = threadIdx.x;
    if (t < 128) cnt2[t] = 0;
    __syncthreads();
    const int begin = base[gb], end = endp[gb];
    for (int e = begin + t; e < end; e += 256) {
        const unsigned w = part[e];
        const int dlow = (int)(w >> 17);
        const int s = (int)(w & 131071u);
        const int p = atomicAdd(&cnt2[dlow], 1);
        if (p < CAP) img[dlow * CAP + p] = s;
        else {
            const int q = atomicAdd(ovfn, 1);
            if (q < OVCAP) ovf[q] = make_int2(buck * 128 + dlow, (rel << 20) | s);
        }
    }
    __syncthreads();
    const int node0 = buck * 128;
    const int valid = min(128, N - node0);
    if (valid <= 0) return;
    if (t < valid) cnt[(size_t)rel * N + node0 + t] = cnt2[t];
    const long sb = ((long)rel * N + node0) * CAP;
    for (int i4 = t; i4 < valid * 4; i4 += 256)
        *reinterpret_cast<int4*>(&slots[sb + (long)i4 * 4]) =
            *reinterpret_cast<const int4*>(&img[i4 * 4]);
}

// ---------------------------------------------------------------------------
// Gather-aggregate + relu: one wave per dst row, quarter-wave edge pairing.
// Lane quarter q handles edge j+q; 16 lanes x uint4(16B) = 256B H row.
// 4 edges in flight per load instruction, 8-edge unrolled main loop.
// ---------------------------------------------------------------------------
__global__ __launch_bounds__(256) void gather_out_kernel(
    const __half* __restrict__ H, const int* __restrict__ cnt,
    const int* __restrict__ slots, const int2* __restrict__ ovf,
    const int* __restrict__ ovfn, float* __restrict__ out, int N, long plane)
{
    const int w = blockIdx.x * 4 + (threadIdx.x >> 6);
    if (w >= N) return;
    const int lane = threadIdx.x & 63;
    const int q = lane >> 4;
    const int c8 = (lane & 15) * 8;

    const int deg0 = cnt[w];
    const int deg1 = cnt[(size_t)N + w];
    const int deg2 = cnt[2 * (size_t)N + w];
    const bool ovr = (deg0 > CAP) | (deg1 > CAP) | (deg2 > CAP);

    float4 accA = make_float4(0.f, 0.f, 0.f, 0.f);
    float4 accB = make_float4(0.f, 0.f, 0.f, 0.f);
    auto acc8 = [&](const uint4& u) {
        const float2 f0 = __half22float2(*reinterpret_cast<const __half2*>(&u.x));
        const float2 f1 = __half22float2(*reinterpret_cast<const __half2*>(&u.y));
        const float2 f2 = __half22float2(*reinterpret_cast<const __half2*>(&u.z));
        const float2 f3 = __half22float2(*reinterpret_cast<const __half2*>(&u.w));
        accA.x += f0.x; accA.y += f0.y; accA.z += f1.x; accA.w += f1.y;
        accB.x += f2.x; accB.y += f2.y; accB.z += f3.x; accB.w += f3.y;
    };

    #pragma unroll
    for (int r = 0; r < 3; ++r) {
        const int deg = (r == 0) ? deg0 : (r == 1) ? deg1 : deg2;
        const int dm = deg < CAP ? deg : CAP;
        if (!dm) continue;
        const __half* __restrict__ Hr = H + (long)r * plane;
        const int* __restrict__ sl = slots + ((size_t)r * N + w) * CAP;
        const int slv = sl[lane & 15];
        int j = 0;
        for (; j + 8 <= dm; j += 8) {
            const int sA = __shfl(slv, j + q);
            const int sB = __shfl(slv, j + 4 + q);
            const uint4 ua = *reinterpret_cast<const uint4*>(Hr + (long)sA * FEAT + c8);
            const uint4 ub = *reinterpret_cast<const uint4*>(Hr + (long)sB * FEAT + c8);
            acc8(ua); acc8(ub);
        }
        for (; j + 4 <= dm; j += 4) {
            const int sA = __shfl(slv, j + q);
            const uint4 ua = *reinterpret_cast<const uint4*>(Hr + (long)sA * FEAT + c8);
            acc8(ua);
        }
        if (j < dm) {
            const int idx = j + q;
            const bool act = idx < dm;
            const int sA = __shfl(slv, act ? idx : 0);
            const uint4 ua = *reinterpret_cast<const uint4*>(Hr + (long)sA * FEAT + c8);
            if (act) acc8(ua);
        }
    }

    if (ovr && q == 0) {          // rare path; pre-reduction, q0 only
        const int n = min(*ovfn, OVCAP);
        for (int k = 0; k < n; ++k) {
            const int2 e = ovf[k];
            if (e.x == w) {
                const int r = e.y >> 20;
                const int s = e.y & ((1 << 20) - 1);
                const uint4 u = *reinterpret_cast<const uint4*>(
                    H + (long)r * plane + (long)s * FEAT + c8);
                acc8(u);
            }
        }
    }

    // reduce quarters (xor 16, then xor 32)
    #pragma unroll
    for (int o = 16; o <= 32; o <<= 1) {
        accA.x += __shfl_xor(accA.x, o); accA.y += __shfl_xor(accA.y, o);
        accA.z += __shfl_xor(accA.z, o); accA.w += __shfl_xor(accA.w, o);
        accB.x += __shfl_xor(accB.x, o); accB.y += __shfl_xor(accB.y, o);
        accB.z += __shfl_xor(accB.z, o); accB.w += __shfl_xor(accB.w, o);
    }

    if (q == 0) {
        float* p = out + (long)w * FEAT + c8;
        *reinterpret_cast<float4*>(p) = make_float4(
            fmaxf(accA.x, 0.f), fmaxf(accA.y, 0.f),
            fmaxf(accA.z, 0.f), fmaxf(accA.w, 0.f));
        *reinterpret_cast<float4*>(p + 4) = make_float4(
            fmaxf(accB.x, 0.f), fmaxf(accB.y, 0.f),
            fmaxf(accB.z, 0.f), fmaxf(accB.w, 0.f));
    }
}

// ---------------------------------------------------------------------------
// Fallback kernels (ws too small / N too large)
// ---------------------------------------------------------------------------
__global__ __launch_bounds__(256) void scatter_kernel(
    const float* __restrict__ x, const int* __restrict__ src,
    const int* __restrict__ dst, float* __restrict__ agg, int E)
{
    long tid = (long)blockIdx.x * blockDim.x + threadIdx.x;
    long e = tid >> 5;
    int  c = (int)(tid & 31) << 2;
    if (e >= E) return;
    int s = src[e];
    int d = dst[e];
    const float4 v = *reinterpret_cast<const float4*>(x + (long)s * FEAT + c);
    float* p = agg + (long)d * FEAT + c;
    atomicAdd(p + 0, v.x);
    atomicAdd(p + 1, v.y);
    atomicAdd(p + 2, v.z);
    atomicAdd(p + 3, v.w);
}

__global__ __launch_bounds__(256) void gemm_acc_kernel(
    const float* __restrict__ A, const float* __restrict__ W,
    float* __restrict__ out, int N, int accum, int relu)
{
    __shared__ float As[16][68];
    __shared__ float Bs[16][128];
    const int t = threadIdx.x;
    const int row0 = blockIdx.x * 64;
    const int cg = t & 31;
    const int rg = t >> 5;
    const int arow = t >> 2;
    const int ac4  = (t & 3) << 2;
    float acc[8][4];
    #pragma unroll
    for (int i = 0; i < 8; ++i)
        #pragma unroll
        for (int j = 0; j < 4; ++j) acc[i][j] = 0.f;
    for (int kb = 0; kb < 8; ++kb) {
        float4 va = make_float4(0.f, 0.f, 0.f, 0.f);
        const int grow = row0 + arow;
        if (grow < N)
            va = *reinterpret_cast<const float4*>(A + (long)grow * FEAT + kb * 16 + ac4);
        __syncthreads();
        As[ac4 + 0][arow] = va.x;
        As[ac4 + 1][arow] = va.y;
        As[ac4 + 2][arow] = va.z;
        As[ac4 + 3][arow] = va.w;
        {
            const int bk = t >> 5;
            const int bc = (t & 31) << 2;
            *reinterpret_cast<float4*>(&Bs[bk][bc]) =
                *reinterpret_cast<const float4*>(W + (long)(kb * 16 + bk) * FEAT + bc);
            *reinterpret_cast<float4*>(&Bs[bk + 8][bc]) =
                *reinterpret_cast<const float4*>(W + (long)(kb * 16 + bk + 8) * FEAT + bc);
        }
        __syncthreads();
        #pragma unroll
        for (int k = 0; k < 16; ++k) {
            float a[8];
            #pragma unroll
            for (int i = 0; i < 8; ++i) a[i] = As[k][rg * 8 + i];
            const float4 b = *reinterpret_cast<const float4*>(&Bs[k][cg * 4]);
            #pragma unroll
            for (int i = 0; i < 8; ++i) {
                acc[i][0] += a[i] * b.x;
                acc[i][1] += a[i] * b.y;
                acc[i][2] += a[i] * b.z;
                acc[i][3] += a[i] * b.w;
            }
        }
    }
    #pragma unroll
    for (int i = 0; i < 8; ++i) {
        const int grow = row0 + rg * 8 + i;
        if (grow >= N) continue;
        float* p = out + (long)grow * FEAT + cg * 4;
        float4 o = make_float4(acc[i][0], acc[i][1], acc[i][2], acc[i][3]);
        if (accum) {
            const float4 prev = *reinterpret_cast<const float4*>(p);
            o.x += prev.x; o.y += prev.y; o.z += prev.z; o.w += prev.w;
        }
        if (relu) {
            o.x = fmaxf(o.x, 0.f); o.y = fmaxf(o.y, 0.f);
            o.z = fmaxf(o.z, 0.f); o.w = fmaxf(o.w, 0.f);
        }
        *reinterpret_cast<float4*>(p) = o;
    }
}

// ---------------------------------------------------------------------------
extern "C" void kernel_launch(void* const* d_in, const int* in_sizes, int n_in,
                              void* d_out, int out_size, void* d_ws, size_t ws_size,
                              hipStream_t stream)
{
    const float* x  = (const float*)d_in[0];
    const float* W0 = (const float*)d_in[1];
    const float* W1 = (const float*)d_in[2];
    const float* W2 = (const float*)d_in[3];
    const int* src0 = (const int*)d_in[4];
    const int* dst0 = (const int*)d_in[5];
    const int* src1 = (const int*)d_in[6];
    const int* dst1 = (const int*)d_in[7];
    const int* src2 = (const int*)d_in[8];
    const int* dst2 = (const int*)d_in[9];
    float* out = (float*)d_out;

    const int N  = in_sizes[0] / FEAT;
    const int E0 = in_sizes[4];
    const int E1 = in_sizes[6];
    const int E2 = in_sizes[8];
    const long Etot = (long)E0 + E1 + E2;
    const long plane = (long)N * FEAT;
    const int NBUK = (N + 127) >> 7;
    const int NB3 = 3 * NBUK;

    // ---- workspace bump allocator (256B aligned chunks) ----
    char* p = (char*)d_ws;
    auto take = [&](size_t bytes) {
        char* r = p;
        p += (bytes + 255) & ~(size_t)255;
        return r;
    };
    __half*    Hh        = (__half*)take((size_t)3 * plane * 2);
    _Float16*  Wt        = (_Float16*)take((size_t)3 * FEAT * FEAT * 2);
    int*       slots     = (int*)take((size_t)3 * N * CAP * 4);
    int*       cnt       = (int*)take((size_t)3 * N * 4);
    unsigned*  part      = (unsigned*)take((size_t)Etot * 4);
    int*       bucketCnt = (int*)take((size_t)(NB3 + 8) * 4);   // + ovfn tail
    int*       ovfn      = bucketCnt + NB3;
    int*       cursor    = (int*)take((size_t)NB3 * 4);
    int*       bucketBase= (int*)take((size_t)NB3 * 4);
    int2*      ovf       = (int2*)take((size_t)OVCAP * 8);
    const size_t needed = (size_t)(p - (char*)d_ws);

    if (ws_size >= needed && N <= 131072 && NBUK <= NBUK_MAX) {
        // 1) Wt = f16 transpose of W
        convw_kernel<<<(3 * FEAT * FEAT + 255) / 256, 256, 0, stream>>>(W0, W1, W2, Wt);
        // 2) H = x @ W (register-W MFMA GEMM)
        h3_kernel<<<(N + 127) / 128, 384, 0, stream>>>(x, Wt, Hh, N, plane);
        // 3) CSR build: partition by dst bucket, then bucket-local sort
        hipMemsetAsync(bucketCnt, 0, (size_t)(NB3 + 8) * 4, stream);
        const int FB0 = (E0 + 8191) / 8192;
        const int FB1 = (E1 + 8191) / 8192;
        const int FB2 = (E2 + 8191) / 8192;
        p1_kernel<<<FB0 + FB1 + FB2, 512, 0, stream>>>(
            dst0, dst1, dst2, bucketCnt, NBUK, E0, E1, E2, FB0, FB1, FB2);
        scan_kernel<<<1, 256, 0, stream>>>(bucketCnt, bucketBase, cursor, NB3);
        p2_kernel<<<FB0 + FB1 + FB2, 512, 0, stream>>>(
            src0, dst0, src1, dst1, src2, dst2,
            cursor, part, NBUK, E0, E1, E2, FB0, FB1, FB2);
        p3_kernel<<<NB3, 256, 0, stream>>>(
            part, bucketBase, cursor, cnt, slots, ovf, ovfn, N, NBUK);
        // 4) gather + relu
        gather_out_kernel<<<(N + 3) / 4, 256, 0, stream>>>(
            Hh, cnt, slots, ovf, ovfn, out, N, plane);
    } else {
        // ---- fallback: sequential scatter + f32 GEMM ----
        float* agg = (float*)d_ws;
        const int* srca[3] = {src0, src1, src2};
        const int* dsta[3] = {dst0, dst1, dst2};
        const float* wa[3] = {W0, W1, W2};
        const int Ea[3] = {E0, E1, E2};
        const int gemm_blocks = (N + 63) / 64;
        for (int r = 0; r < 3; ++r) {
            hipMemsetAsync(d_ws, 0, plane * sizeof(float), stream);
            scatter_kernel<<<((long)Ea[r] * 32 + 255) / 256, 256, 0, stream>>>(
                x, srca[r], dsta[r], agg, Ea[r]);
            gemm_acc_kernel<<<gemm_blocks, 256, 0, stream>>>(
                agg, wa[r], out, N, r > 0, r == 2);
        }
    }
}